// Round 4
// baseline (798.289 us; speedup 1.0000x reference)
//
#include <hip/hip_runtime.h>
#include <hip/hip_bf16.h>
#include <hip/hip_cooperative_groups.h>

namespace cg = cooperative_groups;

#define HIDDEN 64
#define EPS 1e-5f
#define NPB 64            // nodes per block (mm_relu)
#define FNPB 32           // nodes per fused block (4 waves x 8 nodes)
#define WST 72            // bf16 LDS row stride (shorts): 16B-aligned, breaks 128B aliasing

typedef __attribute__((ext_vector_type(8))) short bf16x8;   // MFMA A/B frag (4 VGPRs)
typedef __attribute__((ext_vector_type(4))) float f32x4;    // MFMA C/D frag

__device__ __forceinline__ unsigned short f2b(float x) {
    __hip_bfloat16 b = __float2bfloat16(x);
    return *(unsigned short*)&b;
}
__device__ __forceinline__ float b2f(unsigned short u) {
    unsigned int ui = (unsigned int)u << 16;
    return *(float*)&ui;
}
__device__ __forceinline__ float b2f_lo(unsigned int u) { unsigned int ui = u << 16; return *(float*)&ui; }
__device__ __forceinline__ float b2f_hi(unsigned int u) { unsigned int ui = u & 0xffff0000u; return *(float*)&ui; }
__device__ __forceinline__ unsigned int pk2(float a, float b) {
    return (unsigned int)f2b(a) | ((unsigned int)f2b(b) << 16);
}

// ---------------- CSR build + weight convert: ONE cooperative kernel ----------------
// Replaces memset + hist_rank + block_sum + scan_final + fill + wconv (6 dispatches
// + their launch/drain gaps) with one kernel and 4 grid.sync()s.
// Phase 0: zero cnt, convert weights to bf16, zero dummy m rows.
// Phase 1: histogram + per-edge rank (device-scope atomics).
// Phase 2: per-256-chunk sums.  Phase 3: scan -> row_ptr.  Phase 4: CSR fill.

__global__ __launch_bounds__(256) void csr_coop_kernel(
        const int* __restrict__ row, const int* __restrict__ col,
        const float* __restrict__ cw, const float* __restrict__ hw,
        int* cnt, int* erank, int* bsum, int* row_ptr, int* ecol,
        unsigned short* wbt, unsigned short* mA, unsigned short* mB,
        int n, int e, int L, int nb) {
    cg::grid_group grid = cg::this_grid();
    __shared__ int wsum[4];
    __shared__ int wred[4];
    __shared__ int wexcl[4];
    __shared__ int s_prev;
    __shared__ int s_tot;
    int tid = threadIdx.x;
    int gid = blockIdx.x * 256 + tid;
    int gstride = gridDim.x * 256;

    // ---- phase 0 ----
    for (int i = gid; i < n; i += gstride) cnt[i] = 0;
    int total = 2 * L * 4096;
    for (int i = gid; i < total; i += gstride) {
        int mat = i >> 12;
        int rem = i & 4095;
        const float* src = (mat < L) ? (cw + (size_t)mat * 4096) : (hw + (size_t)(mat - L) * 4096);
        wbt[i] = f2b(src[rem]);
    }
    if (gid < HIDDEN) {
        mA[(size_t)n * HIDDEN + gid] = 0;
        mB[(size_t)n * HIDDEN + gid] = 0;
    }
    grid.sync();

    // ---- phase 1: histogram + rank ----
    for (int i = gid; i < e; i += gstride) {
        int r = row[i];
        erank[i] = atomicAdd(&cnt[r], 1);
    }
    grid.sync();

    // ---- phase 2: per-chunk sums ----
    for (int c = blockIdx.x; c < nb; c += gridDim.x) {
        int i = c * 256 + tid;
        int v = (i < n) ? cnt[i] : 0;
#pragma unroll
        for (int off = 32; off > 0; off >>= 1) v += __shfl_xor(v, off, 64);
        if ((tid & 63) == 0) wsum[tid >> 6] = v;
        __syncthreads();
        if (tid == 0) bsum[c] = wsum[0] + wsum[1] + wsum[2] + wsum[3];
        __syncthreads();
    }
    grid.sync();

    // ---- phase 3: scan -> row_ptr ----
    for (int c = blockIdx.x; c < nb; c += gridDim.x) {
        int lane = tid & 63, w = tid >> 6;
        int acc = 0;
        for (int j = tid; j < c; j += 256) acc += bsum[j];
#pragma unroll
        for (int off = 32; off > 0; off >>= 1) acc += __shfl_xor(acc, off, 64);
        if (lane == 0) wred[w] = acc;
        int i = c * 256 + tid;
        int v = (i < n) ? cnt[i] : 0;
        int sc = v;
#pragma unroll
        for (int off = 1; off < 64; off <<= 1) {
            int t = __shfl_up(sc, off, 64);
            if (lane >= off) sc += t;
        }
        if (lane == 63) wsum[w] = sc;
        __syncthreads();
        if (tid == 0) {
            s_prev = wred[0] + wred[1] + wred[2] + wred[3];
            int a = 0;
#pragma unroll
            for (int j = 0; j < 4; j++) { wexcl[j] = a; a += wsum[j]; }
            s_tot = a;
        }
        __syncthreads();
        if (i < n) row_ptr[i] = s_prev + wexcl[w] + (sc - v);
        if (c == nb - 1 && tid == 0) row_ptr[n] = s_prev + s_tot;
        __syncthreads();
    }
    grid.sync();

    // ---- phase 4: CSR fill ----
    for (int i = gid; i < e; i += gstride) {
        int r = row[i];
        ecol[row_ptr[r] + erank[i]] = col[i];
    }
}

// ---------------- MFMA helpers ----------------
// A tile: s_a[node][k] bf16 stride WST; wave computes rows wbase..wbase+15.
// B tile: s_b[o][k] bf16 stride WST. D layout: col=l16, row=quad*4+reg.

__device__ __forceinline__ void mfma_tile(const unsigned short* s_a,
                                          const unsigned short* s_b,
                                          int l16, int quad, int wbase, f32x4 acc[4]) {
    const unsigned short* ap = &s_a[(size_t)(wbase + l16) * WST + quad * 8];
    const unsigned short* bp = &s_b[(size_t)l16 * WST + quad * 8];
#pragma unroll
    for (int kt = 0; kt < 2; kt++) {
        bf16x8 a = *(const bf16x8*)(ap + kt * 32);
#pragma unroll
        for (int nt = 0; nt < 4; nt++) {
            bf16x8 b = *(const bf16x8*)(bp + (size_t)nt * 16 * WST + kt * 32);
            acc[nt] = __builtin_amdgcn_mfma_f32_16x16x32_bf16(a, b, acc[nt], 0, 0, 0);
        }
    }
}

// load a 64x64 bf16 weight matrix's B-fragments global -> registers
// (weights are L2-hot: same 8KB read by every wave)
__device__ __forceinline__ void load_wfrag(const unsigned short* __restrict__ w,
                                           int l16, int quad, bf16x8 wf[8]) {
    const unsigned short* wp = w + (size_t)l16 * 64 + quad * 8;
#pragma unroll
    for (int nt = 0; nt < 4; nt++) {
#pragma unroll
        for (int kt = 0; kt < 2; kt++)
            wf[nt * 2 + kt] = *(const bf16x8*)(wp + (size_t)nt * 16 * 64 + kt * 32);
    }
}

// stage a pre-converted bf16 weight matrix (plain copy into padded LDS rows)
__device__ __forceinline__ void stage_wb(const unsigned short* __restrict__ wsrc,
                                         unsigned short* s_wb, int tid) {
    for (int i = tid; i < 512; i += 256) {
        int r = i >> 3, seg = i & 7;
        *(uint4*)(&s_wb[r * WST + seg * 8]) = ((const uint4*)(wsrc + r * 64))[seg];
    }
}

// accumulate 8 bf16 values (one uint4) into p[0..7] — unconditional
__device__ __forceinline__ void acc8(float* p, uint4 u) {
    p[0] += b2f_lo(u.x);
    p[1] += b2f_hi(u.x);
    p[2] += b2f_lo(u.y);
    p[3] += b2f_hi(u.y);
    p[4] += b2f_lo(u.z);
    p[5] += b2f_hi(u.z);
    p[6] += b2f_lo(u.w);
    p[7] += b2f_hi(u.w);
}

// ---------------- initial conv matmul: m = bf16(relu(x @ cw0^T)) ----------------

__global__ __launch_bounds__(256) void mm_relu_kernel(const float* __restrict__ h,
                                                      const unsigned short* __restrict__ wb,
                                                      __hip_bfloat16* __restrict__ m, int n) {
    __shared__ unsigned short s_hb[NPB * WST];
    __shared__ unsigned short s_wb[64 * WST];
    int tid = threadIdx.x;
    int base = blockIdx.x * NPB;
    stage_wb(wb, s_wb, tid);
    for (int i = tid; i < 512; i += 256) {
        int r = i >> 3, seg = i & 7;
        if (base + r < n) {
            const float4* hp = (const float4*)(h + (size_t)(base + r) * HIDDEN + seg * 8);
            float4 ha = hp[0], hb = hp[1];
            uint4 p;
            p.x = pk2(ha.x, ha.y);
            p.y = pk2(ha.z, ha.w);
            p.z = pk2(hb.x, hb.y);
            p.w = pk2(hb.z, hb.w);
            *(uint4*)(&s_hb[r * WST + seg * 8]) = p;
        } else {
            *(uint4*)(&s_hb[r * WST + seg * 8]) = make_uint4(0u, 0u, 0u, 0u);
        }
    }
    __syncthreads();
    int lane = tid & 63, wave = tid >> 6;
    int quad = lane >> 4, l16 = lane & 15;
    int wbase = wave * 16;
    f32x4 acc[4];
    acc[0] = (f32x4){0.f,0.f,0.f,0.f}; acc[1] = (f32x4){0.f,0.f,0.f,0.f};
    acc[2] = (f32x4){0.f,0.f,0.f,0.f}; acc[3] = (f32x4){0.f,0.f,0.f,0.f};
    mfma_tile(s_hb, s_wb, l16, quad, wbase, acc);
    unsigned short* mo = (unsigned short*)m;
#pragma unroll
    for (int r = 0; r < 4; r++) {
        int node = base + wbase + quad * 4 + r;
        if (node < n) {
#pragma unroll
            for (int nt = 0; nt < 4; nt++)
                mo[(size_t)node * HIDDEN + nt * 16 + l16] = f2b(fmaxf(acc[nt][r], 0.f));
        }
    }
}

// ---------------- fused layer kernel ----------------
// Block = 256 thr = 4 waves, 32 nodes (8 per wave). Each wave's MFMA A-tile is
// 16 rows: rows 0-7 = its 8 gathered nodes, rows 8-15 = zero padding (MFMA is
// ~1% util, wasting half a tile is free). Barrier-free: A-tile rows are
// wave-private; both weight matrices are loaded global->register (L2-hot 8KB).
// Phase A: 8 lanes per node, 8 neighbors per iteration -> HALF the serialized
// latency windows of the previous 4-neighbor scheme (iters = ceil(deg/8)) and
// a smaller max-degree tail (max over 8 nodes, not 16). ecol prefetched;
// out-of-range neighbors redirected to the pre-zeroed dummy row n.
// Phase B: hidden MFMA + residual + rmsnorm -> h_new.
// Phase C: MFMA with next conv weights -> relu -> m_out.

__global__ __launch_bounds__(256, 6) void fused_layer_kernel(
        const float* hf, const __hip_bfloat16* hb_in,
        const __hip_bfloat16* __restrict__ m_in,
        const unsigned short* __restrict__ hwb,
        const unsigned short* cwb_next,
        const int* __restrict__ row_ptr, const int* __restrict__ ecol,
        const float* __restrict__ cnw, const float* __restrict__ hnw,
        float* out_f32, __hip_bfloat16* hb_new, __hip_bfloat16* m_out, int n) {
    __shared__ unsigned short s_hb[64 * WST];   // 4 waves x 16 rows
    int tid = threadIdx.x;
    int base = blockIdx.x * FNPB;
    int lane = tid & 63, wave = tid >> 6;

    // ---- Phase A: 8 nodes per wave, 8 lanes (8 cols) per node ----
    int g = lane >> 3;          // node index within wave (0..7)
    int sl = lane & 7;          // 8-column slice (cols 8*sl .. 8*sl+7)
    int gb = lane & ~7;         // first lane of this 8-lane group
    int nl = wave * 16 + g;     // LDS A-tile row for this node
    int node = base + wave * 8 + g;

    // zero the wave's 8 pad rows (A-tile rows 8..15) — off the critical path
    *(uint4*)(&s_hb[(size_t)(wave * 16 + 8 + g) * WST + 8 * sl]) = make_uint4(0u, 0u, 0u, 0u);

    const unsigned short* mi = (const unsigned short*)m_in;

    uint4 q0 = make_uint4(0u, 0u, 0u, 0u);
    if (node < n) {
        float p[8];
        if (hf) {
            const float4* hp = (const float4*)(hf + (size_t)node * HIDDEN + 8 * sl);
            float4 v0 = hp[0], v1 = hp[1];
            p[0]=v0.x; p[1]=v0.y; p[2]=v0.z; p[3]=v0.w;
            p[4]=v1.x; p[5]=v1.y; p[6]=v1.z; p[7]=v1.w;
        } else {
            uint4 u0 = *(const uint4*)((const unsigned short*)hb_in + (size_t)node * HIDDEN + 8 * sl);
            p[0]=b2f_lo(u0.x); p[1]=b2f_hi(u0.x);
            p[2]=b2f_lo(u0.y); p[3]=b2f_hi(u0.y);
            p[4]=b2f_lo(u0.z); p[5]=b2f_hi(u0.z);
            p[6]=b2f_lo(u0.w); p[7]=b2f_hi(u0.w);
        }
        int beg = row_ptr[node];
        int end = row_ptr[node + 1];
        int myc = 0;
        if (beg < end) {
            int idx = beg + sl;
            myc = ecol[idx < end ? idx : end - 1];
        }
        for (int b0 = beg; b0 < end; b0 += 8) {
            int nxt = b0 + 8;
            int nmyc = 0;
            if (nxt < end) {                       // prefetch next iteration's ecol
                int idx = nxt + sl;
                nmyc = ecol[idx < end ? idx : end - 1];
            }
            int cnt = end - b0;
            int cj[8];
#pragma unroll
            for (int j = 0; j < 8; j++) {
                int c = __shfl(myc, gb + j, 64);
                cj[j] = (j < cnt) ? c : n;         // OOB -> pre-zeroed dummy row
            }
            uint4 u[8];
#pragma unroll
            for (int j = 0; j < 8; j++)
                u[j] = *(const uint4*)(mi + (size_t)cj[j] * HIDDEN + 8 * sl);
#pragma unroll
            for (int j = 0; j < 8; j++)
                acc8(p, u[j]);
            myc = nmyc;
        }
        float ss = 0.f;
#pragma unroll
        for (int k = 0; k < 8; k++) ss += p[k] * p[k];
        ss += __shfl_xor(ss, 1, 64);
        ss += __shfl_xor(ss, 2, 64);
        ss += __shfl_xor(ss, 4, 64);
        float inv = rsqrtf(ss * (1.0f / 64.0f) + EPS);
        const float4* cp = (const float4*)(cnw + 8 * sl);
        float4 c0 = cp[0], c1 = cp[1];
        q0.x = pk2(p[0]*inv*c0.x, p[1]*inv*c0.y);
        q0.y = pk2(p[2]*inv*c0.z, p[3]*inv*c0.w);
        q0.z = pk2(p[4]*inv*c1.x, p[5]*inv*c1.y);
        q0.w = pk2(p[6]*inv*c1.z, p[7]*inv*c1.w);
    }
    *(uint4*)(&s_hb[(size_t)nl * WST + 8 * sl]) = q0;
    // NO barrier: A-tile rows are wave-private, weights come from global.

    // ---- Phase B: hidden matmul with register B-fragments ----
    int quad = lane >> 4, l16 = lane & 15;
    int wbase = wave * 16;
    bf16x8 wfh[8];
    load_wfrag(hwb, l16, quad, wfh);
    f32x4 acc[4];
    acc[0] = (f32x4){0.f,0.f,0.f,0.f}; acc[1] = (f32x4){0.f,0.f,0.f,0.f};
    acc[2] = (f32x4){0.f,0.f,0.f,0.f}; acc[3] = (f32x4){0.f,0.f,0.f,0.f};
    {
        const unsigned short* ap = &s_hb[(size_t)(wbase + l16) * WST + quad * 8];
#pragma unroll
        for (int kt = 0; kt < 2; kt++) {
            bf16x8 a = *(const bf16x8*)(ap + kt * 32);
#pragma unroll
            for (int nt = 0; nt < 4; nt++)
                acc[nt] = __builtin_amdgcn_mfma_f32_16x16x32_bf16(a, wfh[nt * 2 + kt], acc[nt], 0, 0, 0);
        }
    }

    float hv[4][4];
    float ssq[4] = {0.f, 0.f, 0.f, 0.f};
#pragma unroll
    for (int r = 0; r < 4; r++) {
        int nr = wbase + quad * 4 + r;
#pragma unroll
        for (int nt = 0; nt < 4; nt++) {
            float hres = b2f(s_hb[(size_t)nr * WST + nt * 16 + l16]);   // pad rows read 0
            float v = hres + fmaxf(acc[nt][r], 0.f);
            hv[r][nt] = v;
            ssq[r] += v * v;
        }
    }
#pragma unroll
    for (int mk = 1; mk <= 8; mk <<= 1) {
#pragma unroll
        for (int r = 0; r < 4; r++) ssq[r] += __shfl_xor(ssq[r], mk, 64);
    }
    // phase C weights issued here (L2-hot): latency hides under norm + stores
    bf16x8 wfc[8];
    if (m_out) load_wfrag(cwb_next, l16, quad, wfc);
    float nwv[4];
#pragma unroll
    for (int nt = 0; nt < 4; nt++) nwv[nt] = hnw[nt * 16 + l16];
#pragma unroll
    for (int r = 0; r < 4; r++) {
        float inv = rsqrtf(ssq[r] * (1.0f / 64.0f) + EPS);
#pragma unroll
        for (int nt = 0; nt < 4; nt++) hv[r][nt] *= inv * nwv[nt];
    }
    if (out_f32) {
#pragma unroll
        for (int r = 0; r < 4; r++) {
            int rr = quad * 4 + r;
            int nd = base + wave * 8 + rr;
            if (rr < 8 && nd < n) {
#pragma unroll
                for (int nt = 0; nt < 4; nt++)
                    out_f32[(size_t)nd * HIDDEN + nt * 16 + l16] = hv[r][nt];
            }
        }
    }
    if (hb_new) {
        unsigned short* ho = (unsigned short*)hb_new;
#pragma unroll
        for (int r = 0; r < 4; r++) {
            int rr = quad * 4 + r;
            int nd = base + wave * 8 + rr;
            if (rr < 8 && nd < n) {
#pragma unroll
                for (int nt = 0; nt < 4; nt++)
                    ho[(size_t)nd * HIDDEN + nt * 16 + l16] = f2b(hv[r][nt]);
            }
        }
    }

    if (!m_out) return;

    // ---- D -> A layout (own rows only; intra-wave, no barrier) ----
    // pad rows have hv == 0 (zero A-row -> acc 0, residual 0) so they stay zero
#pragma unroll
    for (int r = 0; r < 4; r++) {
        int nr = wbase + quad * 4 + r;
#pragma unroll
        for (int nt = 0; nt < 4; nt++)
            s_hb[(size_t)nr * WST + nt * 16 + l16] = f2b(hv[r][nt]);
    }

    // ---- Phase C ----
    f32x4 acc2[4];
    acc2[0] = (f32x4){0.f,0.f,0.f,0.f}; acc2[1] = (f32x4){0.f,0.f,0.f,0.f};
    acc2[2] = (f32x4){0.f,0.f,0.f,0.f}; acc2[3] = (f32x4){0.f,0.f,0.f,0.f};
    {
        const unsigned short* ap = &s_hb[(size_t)(wbase + l16) * WST + quad * 8];
#pragma unroll
        for (int kt = 0; kt < 2; kt++) {
            bf16x8 a = *(const bf16x8*)(ap + kt * 32);
#pragma unroll
            for (int nt = 0; nt < 4; nt++)
                acc2[nt] = __builtin_amdgcn_mfma_f32_16x16x32_bf16(a, wfc[nt * 2 + kt], acc2[nt], 0, 0, 0);
        }
    }
    unsigned short* mo = (unsigned short*)m_out;
#pragma unroll
    for (int r = 0; r < 4; r++) {
        int rr = quad * 4 + r;
        int nd = base + wave * 8 + rr;
        if (rr < 8 && nd < n) {
#pragma unroll
            for (int nt = 0; nt < 4; nt++)
                mo[(size_t)nd * HIDDEN + nt * 16 + l16] = f2b(fmaxf(acc2[nt][r], 0.f));
        }
    }
}

// ---------------- launch ----------------

static inline size_t align_up(size_t x, size_t a) { return (x + a - 1) & ~(a - 1); }

extern "C" void kernel_launch(void* const* d_in, const int* in_sizes, int n_in,
                              void* d_out, int out_size, void* d_ws, size_t ws_size,
                              hipStream_t stream) {
    const float* x       = (const float*)d_in[0];
    const float* conv_w  = (const float*)d_in[1];
    const float* conv_nw = (const float*)d_in[2];
    const float* hid_w   = (const float*)d_in[3];
    const float* hid_nw  = (const float*)d_in[4];
    const int*   row     = (const int*)d_in[5];
    const int*   col     = (const int*)d_in[6];
    float* out = (float*)d_out;

    const int n = in_sizes[0] / HIDDEN;   // 100000
    const int e = in_sizes[5];            // 800000
    const int L = in_sizes[1] / 4096;     // 4

    // workspace layout (m buffers have n+1 rows: row n is the zero dummy row)
    size_t off = 0;
    char* ws = (char*)d_ws;
    __hip_bfloat16* mA = (__hip_bfloat16*)(ws + off);  off = align_up(off + (size_t)(n + 1) * HIDDEN * 2, 16);
    __hip_bfloat16* mB = (__hip_bfloat16*)(ws + off);  off = align_up(off + (size_t)(n + 1) * HIDDEN * 2, 16);
    __hip_bfloat16* hb1 = (__hip_bfloat16*)(ws + off); off = align_up(off + (size_t)n * HIDDEN * 2, 16);
    __hip_bfloat16* hb2 = (__hip_bfloat16*)(ws + off); off = align_up(off + (size_t)n * HIDDEN * 2, 16);
    unsigned short* wbt = (unsigned short*)(ws + off); off = align_up(off + (size_t)2 * L * 4096 * 2, 16);
    int* row_ptr = (int*)(ws + off);           off = align_up(off + (size_t)(n + 1) * 4, 16);
    int* cnt = (int*)(ws + off);               off = align_up(off + (size_t)n * 4, 16);
    int* bsum = (int*)(ws + off);              off = align_up(off + (size_t)1024 * 4, 16);
    int* erank = (int*)(ws + off);             off = align_up(off + (size_t)e * 4, 16);
    int* ecol = (int*)(ws + off);              off = align_up(off + (size_t)e * 4, 16);

    const int nb = (n + 255) / 256;

    // CSR build + weight convert: single cooperative kernel
    {
        const int* row_a = row;
        const int* col_a = col;
        const float* cw_a = conv_w;
        const float* hw_a = hid_w;
        int* cnt_a = cnt;
        int* erank_a = erank;
        int* bsum_a = bsum;
        int* rp_a = row_ptr;
        int* ecol_a = ecol;
        unsigned short* wbt_a = wbt;
        unsigned short* mA_a = (unsigned short*)mA;
        unsigned short* mB_a = (unsigned short*)mB;
        int n_a = n, e_a = e, L_a = L, nb_a = nb;
        void* cargs[] = {
            (void*)&row_a, (void*)&col_a, (void*)&cw_a, (void*)&hw_a,
            (void*)&cnt_a, (void*)&erank_a, (void*)&bsum_a, (void*)&rp_a, (void*)&ecol_a,
            (void*)&wbt_a, (void*)&mA_a, (void*)&mB_a,
            (void*)&n_a, (void*)&e_a, (void*)&L_a, (void*)&nb_a };
        hipLaunchCooperativeKernel((const void*)csr_coop_kernel,
                                   dim3(1024), dim3(256), cargs, 0, stream);
    }

    // initial conv matmul for layer 0
    mm_relu_kernel<<<(n + NPB - 1) / NPB, 256, 0, stream>>>(x, wbt, mA, n);

    const int fblocks = (n + FNPB - 1) / FNPB;
    const __hip_bfloat16* mi = mA;
    __hip_bfloat16* mo = mB;
    __hip_bfloat16* hin = nullptr;   // layer 0 uses x (f32)
    __hip_bfloat16* hout = hb1;
    for (int l = 0; l < L; l++) {
        bool last = (l == L - 1);
        fused_layer_kernel<<<fblocks, 256, 0, stream>>>(
            (l == 0) ? x : nullptr, hin, mi,
            wbt + (size_t)(L + l) * 4096,
            last ? nullptr : (wbt + (size_t)(l + 1) * 4096),
            row_ptr, ecol,
            conv_nw + (size_t)l * HIDDEN, hid_nw + (size_t)l * HIDDEN,
            last ? out : nullptr,
            last ? nullptr : hout,
            last ? nullptr : mo, n);
        __hip_bfloat16* tmp = (__hip_bfloat16*)mi; mi = mo; mo = tmp;
        hin = hout;
        hout = (hout == hb1) ? hb2 : hb1;
    }
}

// Round 5
// 360.790 us; speedup vs baseline: 2.2126x; 2.2126x over previous
//
#include <hip/hip_runtime.h>
#include <hip/hip_bf16.h>

#define HIDDEN 64
#define EPS 1e-5f
#define NPB 64            // nodes per block (mm_relu)
#define FNPB 32           // nodes per fused block (4 waves x 8 nodes)
#define WST 72            // bf16 LDS row stride (shorts): 16B-aligned, breaks 128B aliasing

typedef __attribute__((ext_vector_type(8))) short bf16x8;   // MFMA A/B frag (4 VGPRs)
typedef __attribute__((ext_vector_type(4))) float f32x4;    // MFMA C/D frag

__device__ __forceinline__ unsigned short f2b(float x) {
    __hip_bfloat16 b = __float2bfloat16(x);
    return *(unsigned short*)&b;
}
__device__ __forceinline__ float b2f(unsigned short u) {
    unsigned int ui = (unsigned int)u << 16;
    return *(float*)&ui;
}
__device__ __forceinline__ float b2f_lo(unsigned int u) { unsigned int ui = u << 16; return *(float*)&ui; }
__device__ __forceinline__ float b2f_hi(unsigned int u) { unsigned int ui = u & 0xffff0000u; return *(float*)&ui; }
__device__ __forceinline__ unsigned int pk2(float a, float b) {
    return (unsigned int)f2b(a) | ((unsigned int)f2b(b) << 16);
}

// ---------------- CSR build (separate dispatches — grid.sync measured at
// ~100us/sync on gfx950 in round 4; launch overhead is far cheaper) ----------------

__global__ __launch_bounds__(256) void hist_rank_kernel(const int* __restrict__ row,
                                                        int* __restrict__ cnt,
                                                        int* __restrict__ erank, int e) {
    int stride = gridDim.x * blockDim.x;
    for (int i = blockIdx.x * blockDim.x + threadIdx.x; i < e; i += stride) {
        int r = row[i];
        erank[i] = atomicAdd(&cnt[r], 1);
    }
}

__global__ __launch_bounds__(256) void block_sum_kernel(const int* __restrict__ cnt,
                                                        int* __restrict__ bsum, int n) {
    __shared__ int wsum[4];
    int tid = threadIdx.x;
    int i = blockIdx.x * 256 + tid;
    int v = (i < n) ? cnt[i] : 0;
#pragma unroll
    for (int off = 32; off > 0; off >>= 1) v += __shfl_xor(v, off, 64);
    if ((tid & 63) == 0) wsum[tid >> 6] = v;
    __syncthreads();
    if (tid == 0) bsum[blockIdx.x] = wsum[0] + wsum[1] + wsum[2] + wsum[3];
}

// scan_final with inline block-prefix: block b sums bsum[0..b) itself
__global__ __launch_bounds__(256) void scan_final_kernel(const int* __restrict__ cnt,
                                                         const int* __restrict__ bsum,
                                                         int* __restrict__ row_ptr,
                                                         int n, int nb) {
    __shared__ int wred[4];
    __shared__ int wsum[4];
    __shared__ int wexcl[4];
    __shared__ int s_prev;
    __shared__ int s_tot;
    int b = blockIdx.x;
    int tid = threadIdx.x;
    int lane = tid & 63;
    int w = tid >> 6;
    int acc = 0;
    for (int j = tid; j < b; j += 256) acc += bsum[j];
#pragma unroll
    for (int off = 32; off > 0; off >>= 1) acc += __shfl_xor(acc, off, 64);
    if (lane == 0) wred[w] = acc;
    int i = b * 256 + tid;
    int v = (i < n) ? cnt[i] : 0;
    int sc = v;
#pragma unroll
    for (int off = 1; off < 64; off <<= 1) {
        int t = __shfl_up(sc, off, 64);
        if (lane >= off) sc += t;
    }
    if (lane == 63) wsum[w] = sc;
    __syncthreads();
    if (tid == 0) {
        s_prev = wred[0] + wred[1] + wred[2] + wred[3];
        int a = 0;
#pragma unroll
        for (int j = 0; j < 4; j++) { wexcl[j] = a; a += wsum[j]; }
        s_tot = a;
    }
    __syncthreads();
    if (i < n) row_ptr[i] = s_prev + wexcl[w] + (sc - v);
    if (b == nb - 1 && tid == 0) row_ptr[n] = s_prev + s_tot;
}

__global__ __launch_bounds__(256) void fill_kernel(const int* __restrict__ row,
                                                   const int* __restrict__ col,
                                                   const int* __restrict__ row_ptr,
                                                   const int* __restrict__ erank,
                                                   int* __restrict__ ecol, int e, int n) {
    int cls = blockIdx.x & 7;
    int sub = blockIdx.x >> 3;
    int nsub = gridDim.x >> 3;
    int lo = (int)(((long long)n * cls) >> 3);
    int hi = (int)(((long long)n * (cls + 1)) >> 3);
    for (int i = sub * 256 + threadIdx.x; i < e; i += nsub * 256) {
        int r = row[i];
        if (r >= lo && r < hi) {
            int pos = row_ptr[r] + erank[i];
            ecol[pos] = col[i];
        }
    }
}

// pre-convert all 2L weight matrices to bf16, [o][k] row-major (= MFMA B layout).
// Tail threads zero the dummy row (index n) of both m buffers — the zero-row
// target for out-of-range gather lanes (adds +0.0f, bit-identical results).
__global__ __launch_bounds__(256) void wconv_kernel(const float* __restrict__ cw,
                                                    const float* __restrict__ hw,
                                                    unsigned short* __restrict__ wbt,
                                                    unsigned short* __restrict__ mA,
                                                    unsigned short* __restrict__ mB,
                                                    int L, int n) {
    int idx = blockIdx.x * blockDim.x + threadIdx.x;
    int total = 2 * L * 4096;
    if (idx < total) {
        int mat = idx >> 12;
        int rem = idx & 4095;
        const float* src = (mat < L) ? (cw + (size_t)mat * 4096) : (hw + (size_t)(mat - L) * 4096);
        wbt[idx] = f2b(src[rem]);
    } else if (idx < total + HIDDEN) {
        int k = idx - total;
        mA[(size_t)n * HIDDEN + k] = 0;
        mB[(size_t)n * HIDDEN + k] = 0;
    }
}

// ---------------- MFMA helpers ----------------
// A tile: s_a[node][k] bf16 stride WST; wave computes rows wbase..wbase+15.
// B tile: s_b[o][k] bf16 stride WST. D layout: col=l16, row=quad*4+reg.

__device__ __forceinline__ void mfma_tile(const unsigned short* s_a,
                                          const unsigned short* s_b,
                                          int l16, int quad, int wbase, f32x4 acc[4]) {
    const unsigned short* ap = &s_a[(size_t)(wbase + l16) * WST + quad * 8];
    const unsigned short* bp = &s_b[(size_t)l16 * WST + quad * 8];
#pragma unroll
    for (int kt = 0; kt < 2; kt++) {
        bf16x8 a = *(const bf16x8*)(ap + kt * 32);
#pragma unroll
        for (int nt = 0; nt < 4; nt++) {
            bf16x8 b = *(const bf16x8*)(bp + (size_t)nt * 16 * WST + kt * 32);
            acc[nt] = __builtin_amdgcn_mfma_f32_16x16x32_bf16(a, b, acc[nt], 0, 0, 0);
        }
    }
}

// load a 64x64 bf16 weight matrix's B-fragments global -> registers
// (weights are L2-hot: same 8KB read by every wave)
__device__ __forceinline__ void load_wfrag(const unsigned short* __restrict__ w,
                                           int l16, int quad, bf16x8 wf[8]) {
    const unsigned short* wp = w + (size_t)l16 * 64 + quad * 8;
#pragma unroll
    for (int nt = 0; nt < 4; nt++) {
#pragma unroll
        for (int kt = 0; kt < 2; kt++)
            wf[nt * 2 + kt] = *(const bf16x8*)(wp + (size_t)nt * 16 * 64 + kt * 32);
    }
}

// stage a pre-converted bf16 weight matrix (plain copy into padded LDS rows)
__device__ __forceinline__ void stage_wb(const unsigned short* __restrict__ wsrc,
                                         unsigned short* s_wb, int tid) {
    for (int i = tid; i < 512; i += 256) {
        int r = i >> 3, seg = i & 7;
        *(uint4*)(&s_wb[r * WST + seg * 8]) = ((const uint4*)(wsrc + r * 64))[seg];
    }
}

// accumulate 8 bf16 values (one uint4) into p[0..7] — unconditional
__device__ __forceinline__ void acc8(float* p, uint4 u) {
    p[0] += b2f_lo(u.x);
    p[1] += b2f_hi(u.x);
    p[2] += b2f_lo(u.y);
    p[3] += b2f_hi(u.y);
    p[4] += b2f_lo(u.z);
    p[5] += b2f_hi(u.z);
    p[6] += b2f_lo(u.w);
    p[7] += b2f_hi(u.w);
}

// ---------------- initial conv matmul: m = bf16(relu(x @ cw0^T)) ----------------

__global__ __launch_bounds__(256) void mm_relu_kernel(const float* __restrict__ h,
                                                      const unsigned short* __restrict__ wb,
                                                      __hip_bfloat16* __restrict__ m, int n) {
    __shared__ unsigned short s_hb[NPB * WST];
    __shared__ unsigned short s_wb[64 * WST];
    int tid = threadIdx.x;
    int base = blockIdx.x * NPB;
    stage_wb(wb, s_wb, tid);
    for (int i = tid; i < 512; i += 256) {
        int r = i >> 3, seg = i & 7;
        if (base + r < n) {
            const float4* hp = (const float4*)(h + (size_t)(base + r) * HIDDEN + seg * 8);
            float4 ha = hp[0], hb = hp[1];
            uint4 p;
            p.x = pk2(ha.x, ha.y);
            p.y = pk2(ha.z, ha.w);
            p.z = pk2(hb.x, hb.y);
            p.w = pk2(hb.z, hb.w);
            *(uint4*)(&s_hb[r * WST + seg * 8]) = p;
        } else {
            *(uint4*)(&s_hb[r * WST + seg * 8]) = make_uint4(0u, 0u, 0u, 0u);
        }
    }
    __syncthreads();
    int lane = tid & 63, wave = tid >> 6;
    int quad = lane >> 4, l16 = lane & 15;
    int wbase = wave * 16;
    f32x4 acc[4];
    acc[0] = (f32x4){0.f,0.f,0.f,0.f}; acc[1] = (f32x4){0.f,0.f,0.f,0.f};
    acc[2] = (f32x4){0.f,0.f,0.f,0.f}; acc[3] = (f32x4){0.f,0.f,0.f,0.f};
    mfma_tile(s_hb, s_wb, l16, quad, wbase, acc);
    unsigned short* mo = (unsigned short*)m;
#pragma unroll
    for (int r = 0; r < 4; r++) {
        int node = base + wbase + quad * 4 + r;
        if (node < n) {
#pragma unroll
            for (int nt = 0; nt < 4; nt++)
                mo[(size_t)node * HIDDEN + nt * 16 + l16] = f2b(fmaxf(acc[nt][r], 0.f));
        }
    }
}

// ---------------- fused layer kernel ----------------
// Block = 256 thr = 4 waves, 32 nodes (8 per wave). Each wave's MFMA A-tile is
// 16 rows: rows 0-7 = its 8 gathered nodes, rows 8-15 = zero padding (MFMA is
// ~1% util, wasting half a tile is free). Barrier-free: A-tile rows are
// wave-private; both weight matrices are loaded global->register (L2-hot 8KB).
// Phase A: 8 lanes per node, 8 neighbors per iteration -> HALF the serialized
// latency windows of the 4-neighbor scheme (iters = ceil(deg/8)) and a smaller
// max-degree tail (max over 8 nodes, not 16). ecol prefetched; out-of-range
// neighbors redirected to the pre-zeroed dummy row n.
// Phase B: hidden MFMA + residual + rmsnorm -> h_new.
// Phase C: MFMA with next conv weights -> relu -> m_out.

__global__ __launch_bounds__(256, 6) void fused_layer_kernel(
        const float* hf, const __hip_bfloat16* hb_in,
        const __hip_bfloat16* __restrict__ m_in,
        const unsigned short* __restrict__ hwb,
        const unsigned short* cwb_next,
        const int* __restrict__ row_ptr, const int* __restrict__ ecol,
        const float* __restrict__ cnw, const float* __restrict__ hnw,
        float* out_f32, __hip_bfloat16* hb_new, __hip_bfloat16* m_out, int n) {
    __shared__ unsigned short s_hb[64 * WST];   // 4 waves x 16 rows
    int tid = threadIdx.x;
    int base = blockIdx.x * FNPB;
    int lane = tid & 63, wave = tid >> 6;

    // ---- Phase A: 8 nodes per wave, 8 lanes (8 cols) per node ----
    int g = lane >> 3;          // node index within wave (0..7)
    int sl = lane & 7;          // 8-column slice (cols 8*sl .. 8*sl+7)
    int gb = lane & ~7;         // first lane of this 8-lane group
    int nl = wave * 16 + g;     // LDS A-tile row for this node
    int node = base + wave * 8 + g;

    // zero the wave's 8 pad rows (A-tile rows 8..15) — off the critical path
    *(uint4*)(&s_hb[(size_t)(wave * 16 + 8 + g) * WST + 8 * sl]) = make_uint4(0u, 0u, 0u, 0u);

    const unsigned short* mi = (const unsigned short*)m_in;

    uint4 q0 = make_uint4(0u, 0u, 0u, 0u);
    if (node < n) {
        float p[8];
        if (hf) {
            const float4* hp = (const float4*)(hf + (size_t)node * HIDDEN + 8 * sl);
            float4 v0 = hp[0], v1 = hp[1];
            p[0]=v0.x; p[1]=v0.y; p[2]=v0.z; p[3]=v0.w;
            p[4]=v1.x; p[5]=v1.y; p[6]=v1.z; p[7]=v1.w;
        } else {
            uint4 u0 = *(const uint4*)((const unsigned short*)hb_in + (size_t)node * HIDDEN + 8 * sl);
            p[0]=b2f_lo(u0.x); p[1]=b2f_hi(u0.x);
            p[2]=b2f_lo(u0.y); p[3]=b2f_hi(u0.y);
            p[4]=b2f_lo(u0.z); p[5]=b2f_hi(u0.z);
            p[6]=b2f_lo(u0.w); p[7]=b2f_hi(u0.w);
        }
        int beg = row_ptr[node];
        int end = row_ptr[node + 1];
        int myc = 0;
        if (beg < end) {
            int idx = beg + sl;
            myc = ecol[idx < end ? idx : end - 1];
        }
        for (int b0 = beg; b0 < end; b0 += 8) {
            int nxt = b0 + 8;
            int nmyc = 0;
            if (nxt < end) {                       // prefetch next iteration's ecol
                int idx = nxt + sl;
                nmyc = ecol[idx < end ? idx : end - 1];
            }
            int cnt = end - b0;
            int cj[8];
#pragma unroll
            for (int j = 0; j < 8; j++) {
                int c = __shfl(myc, gb + j, 64);
                cj[j] = (j < cnt) ? c : n;         // OOB -> pre-zeroed dummy row
            }
            uint4 u[8];
#pragma unroll
            for (int j = 0; j < 8; j++)
                u[j] = *(const uint4*)(mi + (size_t)cj[j] * HIDDEN + 8 * sl);
#pragma unroll
            for (int j = 0; j < 8; j++)
                acc8(p, u[j]);
            myc = nmyc;
        }
        float ss = 0.f;
#pragma unroll
        for (int k = 0; k < 8; k++) ss += p[k] * p[k];
        ss += __shfl_xor(ss, 1, 64);
        ss += __shfl_xor(ss, 2, 64);
        ss += __shfl_xor(ss, 4, 64);
        float inv = rsqrtf(ss * (1.0f / 64.0f) + EPS);
        const float4* cp = (const float4*)(cnw + 8 * sl);
        float4 c0 = cp[0], c1 = cp[1];
        q0.x = pk2(p[0]*inv*c0.x, p[1]*inv*c0.y);
        q0.y = pk2(p[2]*inv*c0.z, p[3]*inv*c0.w);
        q0.z = pk2(p[4]*inv*c1.x, p[5]*inv*c1.y);
        q0.w = pk2(p[6]*inv*c1.z, p[7]*inv*c1.w);
    }
    *(uint4*)(&s_hb[(size_t)nl * WST + 8 * sl]) = q0;
    // NO barrier: A-tile rows are wave-private, weights come from global.

    // ---- Phase B: hidden matmul with register B-fragments ----
    int quad = lane >> 4, l16 = lane & 15;
    int wbase = wave * 16;
    bf16x8 wfh[8];
    load_wfrag(hwb, l16, quad, wfh);
    f32x4 acc[4];
    acc[0] = (f32x4){0.f,0.f,0.f,0.f}; acc[1] = (f32x4){0.f,0.f,0.f,0.f};
    acc[2] = (f32x4){0.f,0.f,0.f,0.f}; acc[3] = (f32x4){0.f,0.f,0.f,0.f};
    {
        const unsigned short* ap = &s_hb[(size_t)(wbase + l16) * WST + quad * 8];
#pragma unroll
        for (int kt = 0; kt < 2; kt++) {
            bf16x8 a = *(const bf16x8*)(ap + kt * 32);
#pragma unroll
            for (int nt = 0; nt < 4; nt++)
                acc[nt] = __builtin_amdgcn_mfma_f32_16x16x32_bf16(a, wfh[nt * 2 + kt], acc[nt], 0, 0, 0);
        }
    }

    float hv[4][4];
    float ssq[4] = {0.f, 0.f, 0.f, 0.f};
#pragma unroll
    for (int r = 0; r < 4; r++) {
        int nr = wbase + quad * 4 + r;
#pragma unroll
        for (int nt = 0; nt < 4; nt++) {
            float hres = b2f(s_hb[(size_t)nr * WST + nt * 16 + l16]);   // pad rows read 0
            float v = hres + fmaxf(acc[nt][r], 0.f);
            hv[r][nt] = v;
            ssq[r] += v * v;
        }
    }
#pragma unroll
    for (int mk = 1; mk <= 8; mk <<= 1) {
#pragma unroll
        for (int r = 0; r < 4; r++) ssq[r] += __shfl_xor(ssq[r], mk, 64);
    }
    // phase C weights issued here (L2-hot): latency hides under norm + stores
    bf16x8 wfc[8];
    if (m_out) load_wfrag(cwb_next, l16, quad, wfc);
    float nwv[4];
#pragma unroll
    for (int nt = 0; nt < 4; nt++) nwv[nt] = hnw[nt * 16 + l16];
#pragma unroll
    for (int r = 0; r < 4; r++) {
        float inv = rsqrtf(ssq[r] * (1.0f / 64.0f) + EPS);
#pragma unroll
        for (int nt = 0; nt < 4; nt++) hv[r][nt] *= inv * nwv[nt];
    }
    if (out_f32) {
#pragma unroll
        for (int r = 0; r < 4; r++) {
            int rr = quad * 4 + r;
            int nd = base + wave * 8 + rr;
            if (rr < 8 && nd < n) {
#pragma unroll
                for (int nt = 0; nt < 4; nt++)
                    out_f32[(size_t)nd * HIDDEN + nt * 16 + l16] = hv[r][nt];
            }
        }
    }
    if (hb_new) {
        unsigned short* ho = (unsigned short*)hb_new;
#pragma unroll
        for (int r = 0; r < 4; r++) {
            int rr = quad * 4 + r;
            int nd = base + wave * 8 + rr;
            if (rr < 8 && nd < n) {
#pragma unroll
                for (int nt = 0; nt < 4; nt++)
                    ho[(size_t)nd * HIDDEN + nt * 16 + l16] = f2b(hv[r][nt]);
            }
        }
    }

    if (!m_out) return;

    // ---- D -> A layout (own rows only; intra-wave, no barrier) ----
    // pad rows have hv == 0 (zero A-row -> acc 0, residual 0) so they stay zero
#pragma unroll
    for (int r = 0; r < 4; r++) {
        int nr = wbase + quad * 4 + r;
#pragma unroll
        for (int nt = 0; nt < 4; nt++)
            s_hb[(size_t)nr * WST + nt * 16 + l16] = f2b(hv[r][nt]);
    }

    // ---- Phase C ----
    f32x4 acc2[4];
    acc2[0] = (f32x4){0.f,0.f,0.f,0.f}; acc2[1] = (f32x4){0.f,0.f,0.f,0.f};
    acc2[2] = (f32x4){0.f,0.f,0.f,0.f}; acc2[3] = (f32x4){0.f,0.f,0.f,0.f};
    {
        const unsigned short* ap = &s_hb[(size_t)(wbase + l16) * WST + quad * 8];
#pragma unroll
        for (int kt = 0; kt < 2; kt++) {
            bf16x8 a = *(const bf16x8*)(ap + kt * 32);
#pragma unroll
            for (int nt = 0; nt < 4; nt++)
                acc2[nt] = __builtin_amdgcn_mfma_f32_16x16x32_bf16(a, wfc[nt * 2 + kt], acc2[nt], 0, 0, 0);
        }
    }
    unsigned short* mo = (unsigned short*)m_out;
#pragma unroll
    for (int r = 0; r < 4; r++) {
        int rr = quad * 4 + r;
        int nd = base + wave * 8 + rr;
        if (rr < 8 && nd < n) {
#pragma unroll
            for (int nt = 0; nt < 4; nt++)
                mo[(size_t)nd * HIDDEN + nt * 16 + l16] = f2b(fmaxf(acc2[nt][r], 0.f));
        }
    }
}

// ---------------- launch ----------------

static inline size_t align_up(size_t x, size_t a) { return (x + a - 1) & ~(a - 1); }

extern "C" void kernel_launch(void* const* d_in, const int* in_sizes, int n_in,
                              void* d_out, int out_size, void* d_ws, size_t ws_size,
                              hipStream_t stream) {
    const float* x       = (const float*)d_in[0];
    const float* conv_w  = (const float*)d_in[1];
    const float* conv_nw = (const float*)d_in[2];
    const float* hid_w   = (const float*)d_in[3];
    const float* hid_nw  = (const float*)d_in[4];
    const int*   row     = (const int*)d_in[5];
    const int*   col     = (const int*)d_in[6];
    float* out = (float*)d_out;

    const int n = in_sizes[0] / HIDDEN;   // 100000
    const int e = in_sizes[5];            // 800000
    const int L = in_sizes[1] / 4096;     // 4

    // workspace layout (m buffers have n+1 rows: row n is the zero dummy row)
    size_t off = 0;
    char* ws = (char*)d_ws;
    __hip_bfloat16* mA = (__hip_bfloat16*)(ws + off);  off = align_up(off + (size_t)(n + 1) * HIDDEN * 2, 16);
    __hip_bfloat16* mB = (__hip_bfloat16*)(ws + off);  off = align_up(off + (size_t)(n + 1) * HIDDEN * 2, 16);
    __hip_bfloat16* hb1 = (__hip_bfloat16*)(ws + off); off = align_up(off + (size_t)n * HIDDEN * 2, 16);
    __hip_bfloat16* hb2 = (__hip_bfloat16*)(ws + off); off = align_up(off + (size_t)n * HIDDEN * 2, 16);
    unsigned short* wbt = (unsigned short*)(ws + off); off = align_up(off + (size_t)2 * L * 4096 * 2, 16);
    int* row_ptr = (int*)(ws + off);           off = align_up(off + (size_t)(n + 1) * 4, 16);
    int* cnt = (int*)(ws + off);               off = align_up(off + (size_t)n * 4, 16);
    int* bsum = (int*)(ws + off);              off = align_up(off + (size_t)1024 * 4, 16);
    int* erank = (int*)(ws + off);             off = align_up(off + (size_t)e * 4, 16);
    int* ecol = (int*)(ws + off);              off = align_up(off + (size_t)e * 4, 16);

    const int nb = (n + 255) / 256;

    // CSR build (once per launch; edges constant across layers)
    hipMemsetAsync(cnt, 0, (size_t)n * 4, stream);
    hist_rank_kernel<<<1024, 256, 0, stream>>>(row, cnt, erank, e);
    block_sum_kernel<<<nb, 256, 0, stream>>>(cnt, bsum, n);
    scan_final_kernel<<<nb, 256, 0, stream>>>(cnt, bsum, row_ptr, n, nb);
    fill_kernel<<<1024, 256, 0, stream>>>(row, col, row_ptr, erank, ecol, e, n);

    // weights -> bf16 once (+ zero dummy rows of mA/mB)
    wconv_kernel<<<(2 * L * 4096 + HIDDEN + 255) / 256, 256, 0, stream>>>(
        conv_w, hid_w, wbt, (unsigned short*)mA, (unsigned short*)mB, L, n);

    // initial conv matmul for layer 0
    mm_relu_kernel<<<(n + NPB - 1) / NPB, 256, 0, stream>>>(x, wbt, mA, n);

    const int fblocks = (n + FNPB - 1) / FNPB;
    const __hip_bfloat16* mi = mA;
    __hip_bfloat16* mo = mB;
    __hip_bfloat16* hin = nullptr;   // layer 0 uses x (f32)
    __hip_bfloat16* hout = hb1;
    for (int l = 0; l < L; l++) {
        bool last = (l == L - 1);
        fused_layer_kernel<<<fblocks, 256, 0, stream>>>(
            (l == 0) ? x : nullptr, hin, mi,
            wbt + (size_t)(L + l) * 4096,
            last ? nullptr : (wbt + (size_t)(l + 1) * 4096),
            row_ptr, ecol,
            conv_nw + (size_t)l * HIDDEN, hid_nw + (size_t)l * HIDDEN,
            last ? out : nullptr,
            last ? nullptr : hout,
            last ? nullptr : mo, n);
        __hip_bfloat16* tmp = (__hip_bfloat16*)mi; mi = mo; mo = tmp;
        hin = hout;
        hout = (hout == hb1) ? hb2 : hb1;
    }
}

// Round 6
// 330.523 us; speedup vs baseline: 2.4152x; 1.0916x over previous
//
#include <hip/hip_runtime.h>
#include <hip/hip_bf16.h>

#define HIDDEN 64
#define EPS 1e-5f
#define NPB 64            // nodes per block (mm_relu part)
#define FNPB 16           // nodes per fused block (1 wave x 16 nodes)
#define WST 72            // bf16 LDS row stride (shorts): 16B-aligned, breaks 128B aliasing

typedef __attribute__((ext_vector_type(8))) short bf16x8;   // MFMA A/B frag (4 VGPRs)
typedef __attribute__((ext_vector_type(4))) float f32x4;    // MFMA C/D frag

__device__ __forceinline__ unsigned short f2b(float x) {
    __hip_bfloat16 b = __float2bfloat16(x);
    return *(unsigned short*)&b;
}
__device__ __forceinline__ float b2f(unsigned short u) {
    unsigned int ui = (unsigned int)u << 16;
    return *(float*)&ui;
}
__device__ __forceinline__ float b2f_lo(unsigned int u) { unsigned int ui = u << 16; return *(float*)&ui; }
__device__ __forceinline__ float b2f_hi(unsigned int u) { unsigned int ui = u & 0xffff0000u; return *(float*)&ui; }
__device__ __forceinline__ unsigned int pk2(float a, float b) {
    return (unsigned int)f2b(a) | ((unsigned int)f2b(b) << 16);
}

// ---------------- CSR build (separate dispatches — grid.sync measured at
// ~100us/sync on gfx950 in round 4; launch overhead is far cheaper) ----------------

// merged: histogram+rank (blocks 0..1023) and weight-convert (blocks >=1024)
__global__ __launch_bounds__(256) void hist_wconv_kernel(
        const int* __restrict__ row, int* __restrict__ cnt, int* __restrict__ erank, int e,
        const float* __restrict__ cw, const float* __restrict__ hw,
        unsigned short* __restrict__ wbt,
        unsigned short* __restrict__ mA, unsigned short* __restrict__ mB,
        int L, int n) {
    int b = blockIdx.x;
    if (b < 1024) {
        int stride = 1024 * 256;
        for (int i = b * 256 + threadIdx.x; i < e; i += stride) {
            int r = row[i];
            erank[i] = atomicAdd(&cnt[r], 1);
        }
    } else {
        int idx = (b - 1024) * 256 + threadIdx.x;
        int total = 2 * L * 4096;
        if (idx < total) {
            int mat = idx >> 12;
            int rem = idx & 4095;
            const float* src = (mat < L) ? (cw + (size_t)mat * 4096) : (hw + (size_t)(mat - L) * 4096);
            wbt[idx] = f2b(src[rem]);
        } else if (idx < total + HIDDEN) {
            int k = idx - total;
            mA[(size_t)n * HIDDEN + k] = 0;   // zero dummy row (OOB gather target)
            mB[(size_t)n * HIDDEN + k] = 0;
        }
    }
}

__global__ __launch_bounds__(256) void block_sum_kernel(const int* __restrict__ cnt,
                                                        int* __restrict__ bsum, int n) {
    __shared__ int wsum[4];
    int tid = threadIdx.x;
    int i = blockIdx.x * 256 + tid;
    int v = (i < n) ? cnt[i] : 0;
#pragma unroll
    for (int off = 32; off > 0; off >>= 1) v += __shfl_xor(v, off, 64);
    if ((tid & 63) == 0) wsum[tid >> 6] = v;
    __syncthreads();
    if (tid == 0) bsum[blockIdx.x] = wsum[0] + wsum[1] + wsum[2] + wsum[3];
}

__global__ __launch_bounds__(256) void scan_final_kernel(const int* __restrict__ cnt,
                                                         const int* __restrict__ bsum,
                                                         int* __restrict__ row_ptr,
                                                         int n, int nb) {
    __shared__ int wred[4];
    __shared__ int wsum[4];
    __shared__ int wexcl[4];
    __shared__ int s_prev;
    __shared__ int s_tot;
    int b = blockIdx.x;
    int tid = threadIdx.x;
    int lane = tid & 63;
    int w = tid >> 6;
    int acc = 0;
    for (int j = tid; j < b; j += 256) acc += bsum[j];
#pragma unroll
    for (int off = 32; off > 0; off >>= 1) acc += __shfl_xor(acc, off, 64);
    if (lane == 0) wred[w] = acc;
    int i = b * 256 + tid;
    int v = (i < n) ? cnt[i] : 0;
    int sc = v;
#pragma unroll
    for (int off = 1; off < 64; off <<= 1) {
        int t = __shfl_up(sc, off, 64);
        if (lane >= off) sc += t;
    }
    if (lane == 63) wsum[w] = sc;
    __syncthreads();
    if (tid == 0) {
        s_prev = wred[0] + wred[1] + wred[2] + wred[3];
        int a = 0;
#pragma unroll
        for (int j = 0; j < 4; j++) { wexcl[j] = a; a += wsum[j]; }
        s_tot = a;
    }
    __syncthreads();
    if (i < n) row_ptr[i] = s_prev + wexcl[w] + (sc - v);
    if (b == nb - 1 && tid == 0) row_ptr[n] = s_prev + s_tot;
}

// ---------------- MFMA helpers ----------------

__device__ __forceinline__ void mfma_tile(const unsigned short* s_a,
                                          const unsigned short* s_b,
                                          int l16, int quad, int wbase, f32x4 acc[4]) {
    const unsigned short* ap = &s_a[(size_t)(wbase + l16) * WST + quad * 8];
    const unsigned short* bp = &s_b[(size_t)l16 * WST + quad * 8];
#pragma unroll
    for (int kt = 0; kt < 2; kt++) {
        bf16x8 a = *(const bf16x8*)(ap + kt * 32);
#pragma unroll
        for (int nt = 0; nt < 4; nt++) {
            bf16x8 b = *(const bf16x8*)(bp + (size_t)nt * 16 * WST + kt * 32);
            acc[nt] = __builtin_amdgcn_mfma_f32_16x16x32_bf16(a, b, acc[nt], 0, 0, 0);
        }
    }
}

// load a 64x64 bf16 weight matrix's B-fragments global -> registers (L2-hot 8KB)
__device__ __forceinline__ void load_wfrag(const unsigned short* __restrict__ w,
                                           int l16, int quad, bf16x8 wf[8]) {
    const unsigned short* wp = w + (size_t)l16 * 64 + quad * 8;
#pragma unroll
    for (int nt = 0; nt < 4; nt++) {
#pragma unroll
        for (int kt = 0; kt < 2; kt++)
            wf[nt * 2 + kt] = *(const bf16x8*)(wp + (size_t)nt * 16 * 64 + kt * 32);
    }
}

__device__ __forceinline__ void stage_wb(const unsigned short* __restrict__ wsrc,
                                         unsigned short* s_wb, int tid) {
    for (int i = tid; i < 512; i += 256) {
        int r = i >> 3, seg = i & 7;
        *(uint4*)(&s_wb[r * WST + seg * 8]) = ((const uint4*)(wsrc + r * 64))[seg];
    }
}

// accumulate 8 bf16 values (one uint4) into p[0..7] — unconditional
__device__ __forceinline__ void acc8(float* p, uint4 u) {
    p[0] += b2f_lo(u.x);
    p[1] += b2f_hi(u.x);
    p[2] += b2f_lo(u.y);
    p[3] += b2f_hi(u.y);
    p[4] += b2f_lo(u.z);
    p[5] += b2f_hi(u.z);
    p[6] += b2f_lo(u.w);
    p[7] += b2f_hi(u.w);
}

// issue one neighbor-block's gather loads (4 neighbors x 32B slice per lane)
__device__ __forceinline__ void gather4(const unsigned short* __restrict__ mi,
                                        int ec, int cnt, int gb, int sl, int n,
                                        uint4 ua[4], uint4 ub[4]) {
#pragma unroll
    for (int j = 0; j < 4; j++) {
        int c = __shfl(ec, gb + j, 64);
        int cj = (j < cnt) ? c : n;            // OOB -> pre-zeroed dummy row
        const uint4* mp = (const uint4*)(mi + (size_t)cj * HIDDEN + 16 * sl);
        ua[j] = mp[0];
        ub[j] = mp[1];
    }
}

// ---------------- merged fill + initial conv matmul ----------------
// blocks [0, mmblocks): m = bf16(relu(x @ cw0^T)); blocks >= mmblocks: CSR fill.
// Independent work (mm needs wbt; fill needs row_ptr+erank) — both ready.

__global__ __launch_bounds__(256) void fill_mm_kernel(
        const int* __restrict__ row, const int* __restrict__ col,
        const int* __restrict__ row_ptr, const int* __restrict__ erank,
        int* __restrict__ ecol, int e, int n,
        const float* __restrict__ h, const unsigned short* __restrict__ wb,
        __hip_bfloat16* __restrict__ m, int mmblocks) {
    __shared__ unsigned short s_hb[NPB * WST];
    __shared__ unsigned short s_wb[64 * WST];
    int tid = threadIdx.x;
    if ((int)blockIdx.x >= mmblocks) {
        // ---- CSR fill (1024 blocks, 8 row-classes) ----
        int bid = blockIdx.x - mmblocks;
        int cls = bid & 7;
        int sub = bid >> 3;
        int nsub = 128;
        int lo = (int)(((long long)n * cls) >> 3);
        int hi = (int)(((long long)n * (cls + 1)) >> 3);
        for (int i = sub * 256 + tid; i < e; i += nsub * 256) {
            int r = row[i];
            if (r >= lo && r < hi) {
                int pos = row_ptr[r] + erank[i];
                ecol[pos] = col[i];
            }
        }
        return;
    }
    // ---- mm_relu ----
    int base = blockIdx.x * NPB;
    stage_wb(wb, s_wb, tid);
    for (int i = tid; i < 512; i += 256) {
        int r = i >> 3, seg = i & 7;
        if (base + r < n) {
            const float4* hp = (const float4*)(h + (size_t)(base + r) * HIDDEN + seg * 8);
            float4 ha = hp[0], hb = hp[1];
            uint4 p;
            p.x = pk2(ha.x, ha.y);
            p.y = pk2(ha.z, ha.w);
            p.z = pk2(hb.x, hb.y);
            p.w = pk2(hb.z, hb.w);
            *(uint4*)(&s_hb[r * WST + seg * 8]) = p;
        } else {
            *(uint4*)(&s_hb[r * WST + seg * 8]) = make_uint4(0u, 0u, 0u, 0u);
        }
    }
    __syncthreads();
    int lane = tid & 63, wave = tid >> 6;
    int quad = lane >> 4, l16 = lane & 15;
    int wbase = wave * 16;
    f32x4 acc[4];
    acc[0] = (f32x4){0.f,0.f,0.f,0.f}; acc[1] = (f32x4){0.f,0.f,0.f,0.f};
    acc[2] = (f32x4){0.f,0.f,0.f,0.f}; acc[3] = (f32x4){0.f,0.f,0.f,0.f};
    mfma_tile(s_hb, s_wb, l16, quad, wbase, acc);
    unsigned short* mo = (unsigned short*)m;
#pragma unroll
    for (int r = 0; r < 4; r++) {
        int node = base + wbase + quad * 4 + r;
        if (node < n) {
#pragma unroll
            for (int nt = 0; nt < 4; nt++)
                mo[(size_t)node * HIDDEN + nt * 16 + l16] = f2b(fmaxf(acc[nt][r], 0.f));
        }
    }
}

// ---------------- fused layer kernel ----------------
// Block = 64 thr = 1 wave, 16 nodes = exactly its MFMA A-tile rows. Barrier-free;
// both weight matrices global->register (L2-hot). LDS = 2.3KB A-tile only.
// Grid = 6250 blocks: finest load-balance granularity (a high-degree straggler
// wave holds no other waves' resources).
// Phase A: 4 lanes/node, 2-DEEP SOFTWARE PIPELINE — rows for neighbor-block i+1
// and ecol for block i+2 are issued BEFORE accumulating block i, so the ~256cyc
// accumulate hides under the next block's load latency (attacks the measured
// all-waves-waiting state: VALUBusy 22%, MfmaUtil 2%, occupancy 48% in r5).
// OOB neighbors -> pre-zeroed dummy row n. launch_bounds(64,5): VGPR cap ~102
// so the prefetch registers don't spill; 20 waves/CU.
// Phase B: hidden MFMA + residual + rmsnorm -> h_new.  Phase C: next conv
// MFMA -> relu -> m_out.

__global__ __launch_bounds__(64, 5) void fused_layer_kernel(
        const float* hf, const __hip_bfloat16* hb_in,
        const __hip_bfloat16* __restrict__ m_in,
        const unsigned short* __restrict__ hwb,
        const unsigned short* cwb_next,
        const int* __restrict__ row_ptr, const int* __restrict__ ecol,
        const float* __restrict__ cnw, const float* __restrict__ hnw,
        float* out_f32, __hip_bfloat16* hb_new, __hip_bfloat16* m_out, int n) {
    __shared__ unsigned short s_hb[FNPB * WST];   // 16 rows, 2304 B
    int lane = threadIdx.x & 63;
    int base = blockIdx.x * FNPB;

    // ---- Phase A: 16 nodes, 4 lanes (16 cols) per node ----
    int g = lane >> 2;          // node index (0..15) = A-tile row
    int sl = lane & 3;          // 16-column slice
    int gb = lane & ~3;         // first lane of this 4-lane group
    int node = base + g;

    const unsigned short* mi = (const unsigned short*)m_in;

    uint4 q0 = make_uint4(0u, 0u, 0u, 0u);
    uint4 q1 = make_uint4(0u, 0u, 0u, 0u);
    if (node < n) {
        float p[16];
        if (hf) {
            const float4* hp = (const float4*)(hf + (size_t)node * HIDDEN + 16 * sl);
            float4 v0 = hp[0], v1 = hp[1], v2 = hp[2], v3 = hp[3];
            p[0]=v0.x;  p[1]=v0.y;  p[2]=v0.z;  p[3]=v0.w;
            p[4]=v1.x;  p[5]=v1.y;  p[6]=v1.z;  p[7]=v1.w;
            p[8]=v2.x;  p[9]=v2.y;  p[10]=v2.z; p[11]=v2.w;
            p[12]=v3.x; p[13]=v3.y; p[14]=v3.z; p[15]=v3.w;
        } else {
            const uint4* hp = (const uint4*)((const unsigned short*)hb_in + (size_t)node * HIDDEN + 16 * sl);
            uint4 u0 = hp[0], u1 = hp[1];
            p[0]=b2f_lo(u0.x);  p[1]=b2f_hi(u0.x);
            p[2]=b2f_lo(u0.y);  p[3]=b2f_hi(u0.y);
            p[4]=b2f_lo(u0.z);  p[5]=b2f_hi(u0.z);
            p[6]=b2f_lo(u0.w);  p[7]=b2f_hi(u0.w);
            p[8]=b2f_lo(u1.x);  p[9]=b2f_hi(u1.x);
            p[10]=b2f_lo(u1.y); p[11]=b2f_hi(u1.y);
            p[12]=b2f_lo(u1.z); p[13]=b2f_hi(u1.z);
            p[14]=b2f_lo(u1.w); p[15]=b2f_hi(u1.w);
        }
        int beg = row_ptr[node];
        int end = row_ptr[node + 1];
        if (beg < end) {
            // prime the pipeline: ecol for block 0 and block 1, rows for block 0
            int idx0 = beg + sl;
            int ec_cur = ecol[idx0 < end ? idx0 : end - 1];
            int ec_nxt = 0;
            if (beg + 4 < end) {
                int idx1 = beg + 4 + sl;
                ec_nxt = ecol[idx1 < end ? idx1 : end - 1];
            }
            uint4 ua[4], ub[4];
            gather4(mi, ec_cur, end - beg, gb, sl, n, ua, ub);
            for (int b0 = beg; b0 < end; b0 += 4) {
                int n1 = b0 + 4;
                int n2 = b0 + 8;
                int ec_nn = 0;
                if (n2 < end) {                    // prefetch ecol two blocks ahead
                    int idx = n2 + sl;
                    ec_nn = ecol[idx < end ? idx : end - 1];
                }
                bool have_next = (n1 < end);
                uint4 na[4], nb[4];
                if (have_next)                     // issue next block's rows NOW
                    gather4(mi, ec_nxt, end - n1, gb, sl, n, na, nb);
                // accumulate current block (hides next block's load latency)
#pragma unroll
                for (int j = 0; j < 4; j++) { acc8(p, ua[j]); acc8(p + 8, ub[j]); }
                if (have_next) {
#pragma unroll
                    for (int j = 0; j < 4; j++) { ua[j] = na[j]; ub[j] = nb[j]; }
                }
                ec_nxt = ec_nn;
            }
        }
        float ss = 0.f;
#pragma unroll
        for (int k = 0; k < 16; k++) ss += p[k] * p[k];
        ss += __shfl_xor(ss, 1, 64);
        ss += __shfl_xor(ss, 2, 64);
        float inv = rsqrtf(ss * (1.0f / 64.0f) + EPS);
        const float4* cp = (const float4*)(cnw + 16 * sl);
        float4 c0 = cp[0], c1 = cp[1], c2 = cp[2], c3 = cp[3];
        q0.x = pk2(p[0]*inv*c0.x,  p[1]*inv*c0.y);
        q0.y = pk2(p[2]*inv*c0.z,  p[3]*inv*c0.w);
        q0.z = pk2(p[4]*inv*c1.x,  p[5]*inv*c1.y);
        q0.w = pk2(p[6]*inv*c1.z,  p[7]*inv*c1.w);
        q1.x = pk2(p[8]*inv*c2.x,  p[9]*inv*c2.y);
        q1.y = pk2(p[10]*inv*c2.z, p[11]*inv*c2.w);
        q1.z = pk2(p[12]*inv*c3.x, p[13]*inv*c3.y);
        q1.w = pk2(p[14]*inv*c3.z, p[15]*inv*c3.w);
    }
    *(uint4*)(&s_hb[(size_t)g * WST + 16 * sl]) = q0;
    *(uint4*)(&s_hb[(size_t)g * WST + 16 * sl + 8]) = q1;
    // NO barrier: single wave owns all 16 A-tile rows; weights come from global.

    // ---- Phase B: hidden matmul with register B-fragments ----
    int quad = lane >> 4, l16 = lane & 15;
    bf16x8 wfh[8];
    load_wfrag(hwb, l16, quad, wfh);
    f32x4 acc[4];
    acc[0] = (f32x4){0.f,0.f,0.f,0.f}; acc[1] = (f32x4){0.f,0.f,0.f,0.f};
    acc[2] = (f32x4){0.f,0.f,0.f,0.f}; acc[3] = (f32x4){0.f,0.f,0.f,0.f};
    {
        const unsigned short* ap = &s_hb[(size_t)l16 * WST + quad * 8];
#pragma unroll
        for (int kt = 0; kt < 2; kt++) {
            bf16x8 a = *(const bf16x8*)(ap + kt * 32);
#pragma unroll
            for (int nt = 0; nt < 4; nt++)
                acc[nt] = __builtin_amdgcn_mfma_f32_16x16x32_bf16(a, wfh[nt * 2 + kt], acc[nt], 0, 0, 0);
        }
    }

    float hv[4][4];
    float ssq[4] = {0.f, 0.f, 0.f, 0.f};
#pragma unroll
    for (int r = 0; r < 4; r++) {
        int nr = quad * 4 + r;
#pragma unroll
        for (int nt = 0; nt < 4; nt++) {
            float hres = b2f(s_hb[(size_t)nr * WST + nt * 16 + l16]);
            float v = hres + fmaxf(acc[nt][r], 0.f);
            hv[r][nt] = v;
            ssq[r] += v * v;
        }
    }
#pragma unroll
    for (int mk = 1; mk <= 8; mk <<= 1) {
#pragma unroll
        for (int r = 0; r < 4; r++) ssq[r] += __shfl_xor(ssq[r], mk, 64);
    }
    bf16x8 wfc[8];
    if (m_out) load_wfrag(cwb_next, l16, quad, wfc);   // L2-hot, hides under norm+stores
    float nwv[4];
#pragma unroll
    for (int nt = 0; nt < 4; nt++) nwv[nt] = hnw[nt * 16 + l16];
#pragma unroll
    for (int r = 0; r < 4; r++) {
        float inv = rsqrtf(ssq[r] * (1.0f / 64.0f) + EPS);
#pragma unroll
        for (int nt = 0; nt < 4; nt++) hv[r][nt] *= inv * nwv[nt];
    }
    if (out_f32) {
#pragma unroll
        for (int r = 0; r < 4; r++) {
            int nd = base + quad * 4 + r;
            if (nd < n) {
#pragma unroll
                for (int nt = 0; nt < 4; nt++)
                    out_f32[(size_t)nd * HIDDEN + nt * 16 + l16] = hv[r][nt];
            }
        }
    }
    if (hb_new) {
        unsigned short* ho = (unsigned short*)hb_new;
#pragma unroll
        for (int r = 0; r < 4; r++) {
            int nd = base + quad * 4 + r;
            if (nd < n) {
#pragma unroll
                for (int nt = 0; nt < 4; nt++)
                    ho[(size_t)nd * HIDDEN + nt * 16 + l16] = f2b(hv[r][nt]);
            }
        }
    }

    if (!m_out) return;

    // ---- D -> A layout (intra-wave, no barrier) ----
#pragma unroll
    for (int r = 0; r < 4; r++) {
        int nr = quad * 4 + r;
#pragma unroll
        for (int nt = 0; nt < 4; nt++)
            s_hb[(size_t)nr * WST + nt * 16 + l16] = f2b(hv[r][nt]);
    }

    // ---- Phase C ----
    f32x4 acc2[4];
    acc2[0] = (f32x4){0.f,0.f,0.f,0.f}; acc2[1] = (f32x4){0.f,0.f,0.f,0.f};
    acc2[2] = (f32x4){0.f,0.f,0.f,0.f}; acc2[3] = (f32x4){0.f,0.f,0.f,0.f};
    {
        const unsigned short* ap = &s_hb[(size_t)l16 * WST + quad * 8];
#pragma unroll
        for (int kt = 0; kt < 2; kt++) {
            bf16x8 a = *(const bf16x8*)(ap + kt * 32);
#pragma unroll
            for (int nt = 0; nt < 4; nt++)
                acc2[nt] = __builtin_amdgcn_mfma_f32_16x16x32_bf16(a, wfc[nt * 2 + kt], acc2[nt], 0, 0, 0);
        }
    }
    unsigned short* mo = (unsigned short*)m_out;
#pragma unroll
    for (int r = 0; r < 4; r++) {
        int nd = base + quad * 4 + r;
        if (nd < n) {
#pragma unroll
            for (int nt = 0; nt < 4; nt++)
                mo[(size_t)nd * HIDDEN + nt * 16 + l16] = f2b(fmaxf(acc2[nt][r], 0.f));
        }
    }
}

// ---------------- launch ----------------

static inline size_t align_up(size_t x, size_t a) { return (x + a - 1) & ~(a - 1); }

extern "C" void kernel_launch(void* const* d_in, const int* in_sizes, int n_in,
                              void* d_out, int out_size, void* d_ws, size_t ws_size,
                              hipStream_t stream) {
    const float* x       = (const float*)d_in[0];
    const float* conv_w  = (const float*)d_in[1];
    const float* conv_nw = (const float*)d_in[2];
    const float* hid_w   = (const float*)d_in[3];
    const float* hid_nw  = (const float*)d_in[4];
    const int*   row     = (const int*)d_in[5];
    const int*   col     = (const int*)d_in[6];
    float* out = (float*)d_out;

    const int n = in_sizes[0] / HIDDEN;   // 100000
    const int e = in_sizes[5];            // 800000
    const int L = in_sizes[1] / 4096;     // 4

    // workspace layout (m buffers have n+1 rows: row n is the zero dummy row)
    size_t off = 0;
    char* ws = (char*)d_ws;
    __hip_bfloat16* mA = (__hip_bfloat16*)(ws + off);  off = align_up(off + (size_t)(n + 1) * HIDDEN * 2, 16);
    __hip_bfloat16* mB = (__hip_bfloat16*)(ws + off);  off = align_up(off + (size_t)(n + 1) * HIDDEN * 2, 16);
    __hip_bfloat16* hb1 = (__hip_bfloat16*)(ws + off); off = align_up(off + (size_t)n * HIDDEN * 2, 16);
    __hip_bfloat16* hb2 = (__hip_bfloat16*)(ws + off); off = align_up(off + (size_t)n * HIDDEN * 2, 16);
    unsigned short* wbt = (unsigned short*)(ws + off); off = align_up(off + (size_t)2 * L * 4096 * 2, 16);
    int* row_ptr = (int*)(ws + off);           off = align_up(off + (size_t)(n + 1) * 4, 16);
    int* cnt = (int*)(ws + off);               off = align_up(off + (size_t)n * 4, 16);
    int* bsum = (int*)(ws + off);              off = align_up(off + (size_t)1024 * 4, 16);
    int* erank = (int*)(ws + off);             off = align_up(off + (size_t)e * 4, 16);
    int* ecol = (int*)(ws + off);              off = align_up(off + (size_t)e * 4, 16);

    const int nb = (n + 255) / 256;
    const int wconv_blocks = (2 * L * 4096 + HIDDEN + 255) / 256;
    const int mmblocks = (n + NPB - 1) / NPB;

    // CSR build + weight convert (merged where independent)
    hipMemsetAsync(cnt, 0, (size_t)n * 4, stream);
    hist_wconv_kernel<<<1024 + wconv_blocks, 256, 0, stream>>>(
        row, cnt, erank, e, conv_w, hid_w, wbt,
        (unsigned short*)mA, (unsigned short*)mB, L, n);
    block_sum_kernel<<<nb, 256, 0, stream>>>(cnt, bsum, n);
    scan_final_kernel<<<nb, 256, 0, stream>>>(cnt, bsum, row_ptr, n, nb);
    fill_mm_kernel<<<mmblocks + 1024, 256, 0, stream>>>(
        row, col, row_ptr, erank, ecol, e, n, x, wbt, mA, mmblocks);

    const int fblocks = (n + FNPB - 1) / FNPB;   // 6250 single-wave blocks
    const __hip_bfloat16* mi = mA;
    __hip_bfloat16* mo = mB;
    __hip_bfloat16* hin = nullptr;   // layer 0 uses x (f32)
    __hip_bfloat16* hout = hb1;
    for (int l = 0; l < L; l++) {
        bool last = (l == L - 1);
        fused_layer_kernel<<<fblocks, 64, 0, stream>>>(
            (l == 0) ? x : nullptr, hin, mi,
            wbt + (size_t)(L + l) * 4096,
            last ? nullptr : (wbt + (size_t)(l + 1) * 4096),
            row_ptr, ecol,
            conv_nw + (size_t)l * HIDDEN, hid_nw + (size_t)l * HIDDEN,
            last ? out : nullptr,
            last ? nullptr : hout,
            last ? nullptr : mo, n);
        __hip_bfloat16* tmp = (__hip_bfloat16*)mi; mi = mo; mo = tmp;
        hin = hout;
        hout = (hout == hb1) ? hb2 : hb1;
    }
}

// Round 7
// 291.792 us; speedup vs baseline: 2.7358x; 1.1327x over previous
//
#include <hip/hip_runtime.h>
#include <hip/hip_bf16.h>

#define HIDDEN 64
#define EPS 1e-5f
#define NPB 64            // nodes per block (mm_relu part)
#define FNPB 32           // nodes per fused block (2 waves x 16)
#define WST 72            // bf16 LDS row stride (shorts): 16B-aligned, breaks 128B aliasing
#define NBIN 33           // degree bins for counting sort (deg clamped to 32)

typedef __attribute__((ext_vector_type(8))) short bf16x8;   // MFMA A/B frag (4 VGPRs)
typedef __attribute__((ext_vector_type(4))) float f32x4;    // MFMA C/D frag

__device__ __forceinline__ unsigned short f2b(float x) {
    __hip_bfloat16 b = __float2bfloat16(x);
    return *(unsigned short*)&b;
}
__device__ __forceinline__ float b2f(unsigned short u) {
    unsigned int ui = (unsigned int)u << 16;
    return *(float*)&ui;
}
__device__ __forceinline__ float b2f_lo(unsigned int u) { unsigned int ui = u << 16; return *(float*)&ui; }
__device__ __forceinline__ float b2f_hi(unsigned int u) { unsigned int ui = u & 0xffff0000u; return *(float*)&ui; }
__device__ __forceinline__ unsigned int pk2(float a, float b) {
    return (unsigned int)f2b(a) | ((unsigned int)f2b(b) << 16);
}

// ---------------- CSR build (separate dispatches — grid.sync measured at
// ~100us/sync on gfx950 in round 4; launch overhead is far cheaper) ----------------

// merged: histogram+rank (blocks 0..1023) and weight-convert (blocks >=1024)
__global__ __launch_bounds__(256) void hist_wconv_kernel(
        const int* __restrict__ row, int* __restrict__ cnt, int* __restrict__ erank, int e,
        const float* __restrict__ cw, const float* __restrict__ hw,
        unsigned short* __restrict__ wbt,
        unsigned short* __restrict__ mA, unsigned short* __restrict__ mB,
        int L, int n) {
    int b = blockIdx.x;
    if (b < 1024) {
        int stride = 1024 * 256;
        for (int i = b * 256 + threadIdx.x; i < e; i += stride) {
            int r = row[i];
            erank[i] = atomicAdd(&cnt[r], 1);
        }
    } else {
        int idx = (b - 1024) * 256 + threadIdx.x;
        int total = 2 * L * 4096;
        if (idx < total) {
            int mat = idx >> 12;
            int rem = idx & 4095;
            const float* src = (mat < L) ? (cw + (size_t)mat * 4096) : (hw + (size_t)(mat - L) * 4096);
            wbt[idx] = f2b(src[rem]);
        } else if (idx < total + HIDDEN) {
            int k = idx - total;
            mA[(size_t)n * HIDDEN + k] = 0;   // zero dummy row (OOB gather target)
            mB[(size_t)n * HIDDEN + k] = 0;
        }
    }
}

// per-256-chunk sums for row_ptr scan + degree-bin histogram (for perm sort)
__global__ __launch_bounds__(256) void block_sum_kernel(const int* __restrict__ cnt,
                                                        int* __restrict__ bsum,
                                                        int* __restrict__ binh, int n) {
    __shared__ int wsum[4];
    __shared__ int lb[NBIN];
    int tid = threadIdx.x;
    if (tid < NBIN) lb[tid] = 0;
    __syncthreads();
    int i = blockIdx.x * 256 + tid;
    int v = (i < n) ? cnt[i] : 0;
    if (i < n) {
        int d = v > 32 ? 32 : v;
        atomicAdd(&lb[d], 1);
    }
#pragma unroll
    for (int off = 32; off > 0; off >>= 1) v += __shfl_xor(v, off, 64);
    if ((tid & 63) == 0) wsum[tid >> 6] = v;
    __syncthreads();
    if (tid == 0) bsum[blockIdx.x] = wsum[0] + wsum[1] + wsum[2] + wsum[3];
    if (tid < NBIN && lb[tid] > 0) atomicAdd(&binh[tid], lb[tid]);
}

// scan -> row_ptr; block 0 additionally turns binh into exclusive bases binb
__global__ __launch_bounds__(256) void scan_final_kernel(const int* __restrict__ cnt,
                                                         const int* __restrict__ bsum,
                                                         int* __restrict__ row_ptr,
                                                         const int* __restrict__ binh,
                                                         int* __restrict__ binb,
                                                         int n, int nb) {
    __shared__ int wred[4];
    __shared__ int wsum[4];
    __shared__ int wexcl[4];
    __shared__ int s_prev;
    __shared__ int s_tot;
    int b = blockIdx.x;
    int tid = threadIdx.x;
    int lane = tid & 63;
    int w = tid >> 6;
    if (b == 0 && tid == 0) {
        int run = 0;
#pragma unroll 1
        for (int j = 0; j < NBIN; j++) { binb[j] = run; run += binh[j]; }
    }
    int acc = 0;
    for (int j = tid; j < b; j += 256) acc += bsum[j];
#pragma unroll
    for (int off = 32; off > 0; off >>= 1) acc += __shfl_xor(acc, off, 64);
    if (lane == 0) wred[w] = acc;
    int i = b * 256 + tid;
    int v = (i < n) ? cnt[i] : 0;
    int sc = v;
#pragma unroll
    for (int off = 1; off < 64; off <<= 1) {
        int t = __shfl_up(sc, off, 64);
        if (lane >= off) sc += t;
    }
    if (lane == 63) wsum[w] = sc;
    __syncthreads();
    if (tid == 0) {
        s_prev = wred[0] + wred[1] + wred[2] + wred[3];
        int a = 0;
#pragma unroll
        for (int j = 0; j < 4; j++) { wexcl[j] = a; a += wsum[j]; }
        s_tot = a;
    }
    __syncthreads();
    if (i < n) row_ptr[i] = s_prev + wexcl[w] + (sc - v);
    if (b == nb - 1 && tid == 0) row_ptr[n] = s_prev + s_tot;
}

// ---------------- MFMA helpers ----------------

__device__ __forceinline__ void mfma_tile(const unsigned short* s_a,
                                          const unsigned short* s_b,
                                          int l16, int quad, int wbase, f32x4 acc[4]) {
    const unsigned short* ap = &s_a[(size_t)(wbase + l16) * WST + quad * 8];
    const unsigned short* bp = &s_b[(size_t)l16 * WST + quad * 8];
#pragma unroll
    for (int kt = 0; kt < 2; kt++) {
        bf16x8 a = *(const bf16x8*)(ap + kt * 32);
#pragma unroll
        for (int nt = 0; nt < 4; nt++) {
            bf16x8 b = *(const bf16x8*)(bp + (size_t)nt * 16 * WST + kt * 32);
            acc[nt] = __builtin_amdgcn_mfma_f32_16x16x32_bf16(a, b, acc[nt], 0, 0, 0);
        }
    }
}

// load a 64x64 bf16 weight matrix's B-fragments global -> registers (L2-hot 8KB)
__device__ __forceinline__ void load_wfrag(const unsigned short* __restrict__ w,
                                           int l16, int quad, bf16x8 wf[8]) {
    const unsigned short* wp = w + (size_t)l16 * 64 + quad * 8;
#pragma unroll
    for (int nt = 0; nt < 4; nt++) {
#pragma unroll
        for (int kt = 0; kt < 2; kt++)
            wf[nt * 2 + kt] = *(const bf16x8*)(wp + (size_t)nt * 16 * 64 + kt * 32);
    }
}

__device__ __forceinline__ void stage_wb(const unsigned short* __restrict__ wsrc,
                                         unsigned short* s_wb, int tid) {
    for (int i = tid; i < 512; i += 256) {
        int r = i >> 3, seg = i & 7;
        *(uint4*)(&s_wb[r * WST + seg * 8]) = ((const uint4*)(wsrc + r * 64))[seg];
    }
}

// accumulate 8 bf16 values (one uint4) into p[0..7] — unconditional
__device__ __forceinline__ void acc8(float* p, uint4 u) {
    p[0] += b2f_lo(u.x);
    p[1] += b2f_hi(u.x);
    p[2] += b2f_lo(u.y);
    p[3] += b2f_hi(u.y);
    p[4] += b2f_lo(u.z);
    p[5] += b2f_hi(u.z);
    p[6] += b2f_lo(u.w);
    p[7] += b2f_hi(u.w);
}

// ---------------- merged fill + initial conv matmul + perm scatter ----------------
// blocks [0, mmblocks):               m = bf16(relu(x @ cw0^T))
// blocks [mmblocks, mmblocks+1024):   CSR fill (8 row-classes x 128 sub)
// blocks [mmblocks+1024, +nb):        degree counting-sort scatter -> perm

__global__ __launch_bounds__(256) void fill_mm_perm_kernel(
        const int* __restrict__ row, const int* __restrict__ col,
        const int* __restrict__ row_ptr, const int* __restrict__ erank,
        int* __restrict__ ecol, int e, int n,
        const float* __restrict__ h, const unsigned short* __restrict__ wb,
        __hip_bfloat16* __restrict__ m,
        const int* __restrict__ cnt, int* __restrict__ binb, int* __restrict__ perm,
        int mmblocks) {
    __shared__ unsigned short s_hb[NPB * WST];
    __shared__ unsigned short s_wb[64 * WST];
    __shared__ int lbin[NBIN];
    __shared__ int lbase[NBIN];
    int tid = threadIdx.x;
    int bid = blockIdx.x;
    if (bid >= mmblocks + 1024) {
        // ---- perm scatter: counting sort by degree, 256 nodes per block ----
        int c = bid - (mmblocks + 1024);
        if (tid < NBIN) lbin[tid] = 0;
        __syncthreads();
        int i = c * 256 + tid;
        int d = -1, rank = 0;
        if (i < n) {
            int dv = cnt[i];
            d = dv > 32 ? 32 : dv;
            rank = atomicAdd(&lbin[d], 1);
        }
        __syncthreads();
        if (tid < NBIN && lbin[tid] > 0) lbase[tid] = atomicAdd(&binb[tid], lbin[tid]);
        __syncthreads();
        if (d >= 0) perm[lbase[d] + rank] = i;
        return;
    }
    if (bid >= mmblocks) {
        // ---- CSR fill (1024 blocks, 8 row-classes) ----
        int fb = bid - mmblocks;
        int cls = fb & 7;
        int sub = fb >> 3;
        int nsub = 128;
        int lo = (int)(((long long)n * cls) >> 3);
        int hi = (int)(((long long)n * (cls + 1)) >> 3);
        for (int i = sub * 256 + tid; i < e; i += nsub * 256) {
            int r = row[i];
            if (r >= lo && r < hi) {
                int pos = row_ptr[r] + erank[i];
                ecol[pos] = col[i];
            }
        }
        return;
    }
    // ---- mm_relu ----
    int base = bid * NPB;
    stage_wb(wb, s_wb, tid);
    for (int i = tid; i < 512; i += 256) {
        int r = i >> 3, seg = i & 7;
        if (base + r < n) {
            const float4* hp = (const float4*)(h + (size_t)(base + r) * HIDDEN + seg * 8);
            float4 ha = hp[0], hb = hp[1];
            uint4 p;
            p.x = pk2(ha.x, ha.y);
            p.y = pk2(ha.z, ha.w);
            p.z = pk2(hb.x, hb.y);
            p.w = pk2(hb.z, hb.w);
            *(uint4*)(&s_hb[r * WST + seg * 8]) = p;
        } else {
            *(uint4*)(&s_hb[r * WST + seg * 8]) = make_uint4(0u, 0u, 0u, 0u);
        }
    }
    __syncthreads();
    int lane = tid & 63, wave = tid >> 6;
    int quad = lane >> 4, l16 = lane & 15;
    int wbase = wave * 16;
    f32x4 acc[4];
    acc[0] = (f32x4){0.f,0.f,0.f,0.f}; acc[1] = (f32x4){0.f,0.f,0.f,0.f};
    acc[2] = (f32x4){0.f,0.f,0.f,0.f}; acc[3] = (f32x4){0.f,0.f,0.f,0.f};
    mfma_tile(s_hb, s_wb, l16, quad, wbase, acc);
    unsigned short* mo = (unsigned short*)m;
#pragma unroll
    for (int r = 0; r < 4; r++) {
        int node = base + wbase + quad * 4 + r;
        if (node < n) {
#pragma unroll
            for (int nt = 0; nt < 4; nt++)
                mo[(size_t)node * HIDDEN + nt * 16 + l16] = f2b(fmaxf(acc[nt][r], 0.f));
        }
    }
}

// ---------------- fused layer kernel ----------------
// Round-3 structure (best measured): 128 thr = 2 waves, 32 nodes; each wave owns
// 16 A-tile rows; barrier-free; both weight matrices global->register.
// NEW: wave k processes nodes perm[32b + 16w .. +15] — degree-sorted, so all 16
// nodes in a wave have ~equal degree. Phase A iterations = ceil(deg/4) uniform
// (~2.2) instead of max-over-16 (~4): the straggler tail that dominated the
// gather phase is gone. All buffers stay in ORIGINAL node order (gather pattern
// unchanged); only per-node row I/O becomes scattered at 128-256B granularity
// (full-line writes, negligible).
// Phase A: 4 lanes/node, ecol prefetch, OOB -> pre-zeroed dummy row n.
// Phase B: hidden MFMA + residual + rmsnorm.  Phase C: next conv MFMA -> relu.

__global__ __launch_bounds__(128, 6) void fused_layer_kernel(
        const float* hf, const __hip_bfloat16* hb_in,
        const __hip_bfloat16* __restrict__ m_in,
        const unsigned short* __restrict__ hwb,
        const unsigned short* cwb_next,
        const int* __restrict__ row_ptr, const int* __restrict__ ecol,
        const int* __restrict__ perm,
        const float* __restrict__ cnw, const float* __restrict__ hnw,
        float* out_f32, __hip_bfloat16* hb_new, __hip_bfloat16* m_out, int n) {
    __shared__ unsigned short s_hb[FNPB * WST];
    int tid = threadIdx.x;
    int base = blockIdx.x * FNPB;
    int lane = tid & 63, wave = tid >> 6;

    // ---- Phase A: 16 nodes per wave, 4 lanes (16 cols) per node ----
    int g = lane >> 2;          // node slot within wave tile (0..15)
    int sl = lane & 3;          // 16-column slice
    int gb = lane & ~3;         // first lane of this 4-lane group
    int nl = wave * 16 + g;     // LDS A-tile row
    int pidx = base + nl;       // position in degree-sorted order
    int node = (pidx < n) ? perm[pidx] : -1;

    const unsigned short* mi = (const unsigned short*)m_in;

    uint4 q0 = make_uint4(0u, 0u, 0u, 0u);
    uint4 q1 = make_uint4(0u, 0u, 0u, 0u);
    if (node >= 0) {
        float p[16];
        if (hf) {
            const float4* hp = (const float4*)(hf + (size_t)node * HIDDEN + 16 * sl);
            float4 v0 = hp[0], v1 = hp[1], v2 = hp[2], v3 = hp[3];
            p[0]=v0.x;  p[1]=v0.y;  p[2]=v0.z;  p[3]=v0.w;
            p[4]=v1.x;  p[5]=v1.y;  p[6]=v1.z;  p[7]=v1.w;
            p[8]=v2.x;  p[9]=v2.y;  p[10]=v2.z; p[11]=v2.w;
            p[12]=v3.x; p[13]=v3.y; p[14]=v3.z; p[15]=v3.w;
        } else {
            const uint4* hp = (const uint4*)((const unsigned short*)hb_in + (size_t)node * HIDDEN + 16 * sl);
            uint4 u0 = hp[0], u1 = hp[1];
            p[0]=b2f_lo(u0.x);  p[1]=b2f_hi(u0.x);
            p[2]=b2f_lo(u0.y);  p[3]=b2f_hi(u0.y);
            p[4]=b2f_lo(u0.z);  p[5]=b2f_hi(u0.z);
            p[6]=b2f_lo(u0.w);  p[7]=b2f_hi(u0.w);
            p[8]=b2f_lo(u1.x);  p[9]=b2f_hi(u1.x);
            p[10]=b2f_lo(u1.y); p[11]=b2f_hi(u1.y);
            p[12]=b2f_lo(u1.z); p[13]=b2f_hi(u1.z);
            p[14]=b2f_lo(u1.w); p[15]=b2f_hi(u1.w);
        }
        int beg = row_ptr[node];
        int end = row_ptr[node + 1];
        int myc = 0;
        if (beg < end) {
            int idx = beg + sl;
            myc = ecol[idx < end ? idx : end - 1];
        }
        for (int b0 = beg; b0 < end; b0 += 4) {
            int nxt = b0 + 4;
            int nmyc = 0;
            if (nxt < end) {                       // prefetch next iteration's ecol
                int idx = nxt + sl;
                nmyc = ecol[idx < end ? idx : end - 1];
            }
            int cnt4 = end - b0;
            int cj[4];
#pragma unroll
            for (int j = 0; j < 4; j++) {
                int c = __shfl(myc, gb + j, 64);
                cj[j] = (j < cnt4) ? c : n;        // OOB -> pre-zeroed dummy row
            }
            uint4 ua[4], ub[4];
#pragma unroll
            for (int j = 0; j < 4; j++) {
                const uint4* mp = (const uint4*)(mi + (size_t)cj[j] * HIDDEN + 16 * sl);
                ua[j] = mp[0];
                ub[j] = mp[1];
            }
#pragma unroll
            for (int j = 0; j < 4; j++) {
                acc8(p, ua[j]);
                acc8(p + 8, ub[j]);
            }
            myc = nmyc;
        }
        float ss = 0.f;
#pragma unroll
        for (int k = 0; k < 16; k++) ss += p[k] * p[k];
        ss += __shfl_xor(ss, 1, 64);
        ss += __shfl_xor(ss, 2, 64);
        float inv = rsqrtf(ss * (1.0f / 64.0f) + EPS);
        const float4* cp = (const float4*)(cnw + 16 * sl);
        float4 c0 = cp[0], c1 = cp[1], c2 = cp[2], c3 = cp[3];
        q0.x = pk2(p[0]*inv*c0.x,  p[1]*inv*c0.y);
        q0.y = pk2(p[2]*inv*c0.z,  p[3]*inv*c0.w);
        q0.z = pk2(p[4]*inv*c1.x,  p[5]*inv*c1.y);
        q0.w = pk2(p[6]*inv*c1.z,  p[7]*inv*c1.w);
        q1.x = pk2(p[8]*inv*c2.x,  p[9]*inv*c2.y);
        q1.y = pk2(p[10]*inv*c2.z, p[11]*inv*c2.w);
        q1.z = pk2(p[12]*inv*c3.x, p[13]*inv*c3.y);
        q1.w = pk2(p[14]*inv*c3.z, p[15]*inv*c3.w);
    }
    *(uint4*)(&s_hb[(size_t)nl * WST + 16 * sl]) = q0;
    *(uint4*)(&s_hb[(size_t)nl * WST + 16 * sl + 8]) = q1;
    // NO barrier: A-tile rows are wave-private, weights come from global.

    // ---- Phase B: hidden matmul with register B-fragments ----
    int quad = lane >> 4, l16 = lane & 15;
    int wbase = wave * 16;
    bf16x8 wfh[8];
    load_wfrag(hwb, l16, quad, wfh);
    f32x4 acc[4];
    acc[0] = (f32x4){0.f,0.f,0.f,0.f}; acc[1] = (f32x4){0.f,0.f,0.f,0.f};
    acc[2] = (f32x4){0.f,0.f,0.f,0.f}; acc[3] = (f32x4){0.f,0.f,0.f,0.f};
    {
        const unsigned short* ap = &s_hb[(size_t)(wbase + l16) * WST + quad * 8];
#pragma unroll
        for (int kt = 0; kt < 2; kt++) {
            bf16x8 a = *(const bf16x8*)(ap + kt * 32);
#pragma unroll
            for (int nt = 0; nt < 4; nt++)
                acc[nt] = __builtin_amdgcn_mfma_f32_16x16x32_bf16(a, wfh[nt * 2 + kt], acc[nt], 0, 0, 0);
        }
    }

    // permuted node ids for this thread's 4 output rows (L1/L2-hot)
    int pr[4];
#pragma unroll
    for (int r = 0; r < 4; r++) {
        int pidx_r = base + wbase + quad * 4 + r;
        pr[r] = (pidx_r < n) ? perm[pidx_r] : -1;
    }

    float hv[4][4];
    float ssq[4] = {0.f, 0.f, 0.f, 0.f};
#pragma unroll
    for (int r = 0; r < 4; r++) {
        int nr = wbase + quad * 4 + r;
#pragma unroll
        for (int nt = 0; nt < 4; nt++) {
            float hres = b2f(s_hb[(size_t)nr * WST + nt * 16 + l16]);
            float v = hres + fmaxf(acc[nt][r], 0.f);
            hv[r][nt] = v;
            ssq[r] += v * v;
        }
    }
#pragma unroll
    for (int mk = 1; mk <= 8; mk <<= 1) {
#pragma unroll
        for (int r = 0; r < 4; r++) ssq[r] += __shfl_xor(ssq[r], mk, 64);
    }
    bf16x8 wfc[8];
    if (m_out) load_wfrag(cwb_next, l16, quad, wfc);   // L2-hot, hides under norm+stores
    float nwv[4];
#pragma unroll
    for (int nt = 0; nt < 4; nt++) nwv[nt] = hnw[nt * 16 + l16];
#pragma unroll
    for (int r = 0; r < 4; r++) {
        float inv = rsqrtf(ssq[r] * (1.0f / 64.0f) + EPS);
#pragma unroll
        for (int nt = 0; nt < 4; nt++) hv[r][nt] *= inv * nwv[nt];
    }
    if (out_f32) {
#pragma unroll
        for (int r = 0; r < 4; r++) {
            if (pr[r] >= 0) {
#pragma unroll
                for (int nt = 0; nt < 4; nt++)
                    out_f32[(size_t)pr[r] * HIDDEN + nt * 16 + l16] = hv[r][nt];
            }
        }
    }
    if (hb_new) {
        unsigned short* ho = (unsigned short*)hb_new;
#pragma unroll
        for (int r = 0; r < 4; r++) {
            if (pr[r] >= 0) {
#pragma unroll
                for (int nt = 0; nt < 4; nt++)
                    ho[(size_t)pr[r] * HIDDEN + nt * 16 + l16] = f2b(hv[r][nt]);
            }
        }
    }

    if (!m_out) return;

    // ---- D -> A layout (own rows only; intra-wave, no barrier) ----
#pragma unroll
    for (int r = 0; r < 4; r++) {
        int nr = wbase + quad * 4 + r;
#pragma unroll
        for (int nt = 0; nt < 4; nt++)
            s_hb[(size_t)nr * WST + nt * 16 + l16] = f2b(hv[r][nt]);
    }

    // ---- Phase C ----
    f32x4 acc2[4];
    acc2[0] = (f32x4){0.f,0.f,0.f,0.f}; acc2[1] = (f32x4){0.f,0.f,0.f,0.f};
    acc2[2] = (f32x4){0.f,0.f,0.f,0.f}; acc2[3] = (f32x4){0.f,0.f,0.f,0.f};
    {
        const unsigned short* ap = &s_hb[(size_t)(wbase + l16) * WST + quad * 8];
#pragma unroll
        for (int kt = 0; kt < 2; kt++) {
            bf16x8 a = *(const bf16x8*)(ap + kt * 32);
#pragma unroll
            for (int nt = 0; nt < 4; nt++)
                acc2[nt] = __builtin_amdgcn_mfma_f32_16x16x32_bf16(a, wfc[nt * 2 + kt], acc2[nt], 0, 0, 0);
        }
    }
    unsigned short* mo = (unsigned short*)m_out;
#pragma unroll
    for (int r = 0; r < 4; r++) {
        if (pr[r] >= 0) {
#pragma unroll
            for (int nt = 0; nt < 4; nt++)
                mo[(size_t)pr[r] * HIDDEN + nt * 16 + l16] = f2b(fmaxf(acc2[nt][r], 0.f));
        }
    }
}

// ---------------- launch ----------------

static inline size_t align_up(size_t x, size_t a) { return (x + a - 1) & ~(a - 1); }

extern "C" void kernel_launch(void* const* d_in, const int* in_sizes, int n_in,
                              void* d_out, int out_size, void* d_ws, size_t ws_size,
                              hipStream_t stream) {
    const float* x       = (const float*)d_in[0];
    const float* conv_w  = (const float*)d_in[1];
    const float* conv_nw = (const float*)d_in[2];
    const float* hid_w   = (const float*)d_in[3];
    const float* hid_nw  = (const float*)d_in[4];
    const int*   row     = (const int*)d_in[5];
    const int*   col     = (const int*)d_in[6];
    float* out = (float*)d_out;

    const int n = in_sizes[0] / HIDDEN;   // 100000
    const int e = in_sizes[5];            // 800000
    const int L = in_sizes[1] / 4096;     // 4

    // workspace layout (m buffers have n+1 rows: row n is the zero dummy row)
    size_t off = 0;
    char* ws = (char*)d_ws;
    __hip_bfloat16* mA = (__hip_bfloat16*)(ws + off);  off = align_up(off + (size_t)(n + 1) * HIDDEN * 2, 16);
    __hip_bfloat16* mB = (__hip_bfloat16*)(ws + off);  off = align_up(off + (size_t)(n + 1) * HIDDEN * 2, 16);
    __hip_bfloat16* hb1 = (__hip_bfloat16*)(ws + off); off = align_up(off + (size_t)n * HIDDEN * 2, 16);
    __hip_bfloat16* hb2 = (__hip_bfloat16*)(ws + off); off = align_up(off + (size_t)n * HIDDEN * 2, 16);
    unsigned short* wbt = (unsigned short*)(ws + off); off = align_up(off + (size_t)2 * L * 4096 * 2, 16);
    int* row_ptr = (int*)(ws + off);           off = align_up(off + (size_t)(n + 1) * 4, 16);
    int* cnt = (int*)(ws + off);               // cnt, binh, binb contiguous (one memset)
    int* binh = cnt + n;
    int* binb = binh + 64;
    off = align_up(off + (size_t)(n + 128) * 4, 16);
    int* perm = (int*)(ws + off);              off = align_up(off + (size_t)n * 4, 16);
    int* bsum = (int*)(ws + off);              off = align_up(off + (size_t)1024 * 4, 16);
    int* erank = (int*)(ws + off);             off = align_up(off + (size_t)e * 4, 16);
    int* ecol = (int*)(ws + off);              off = align_up(off + (size_t)e * 4, 16);

    const int nb = (n + 255) / 256;
    const int wconv_blocks = (2 * L * 4096 + HIDDEN + 255) / 256;
    const int mmblocks = (n + NPB - 1) / NPB;

    // CSR build + weight convert + degree sort (merged where independent)
    hipMemsetAsync(cnt, 0, (size_t)(n + 64) * 4, stream);   // cnt + binh
    hist_wconv_kernel<<<1024 + wconv_blocks, 256, 0, stream>>>(
        row, cnt, erank, e, conv_w, hid_w, wbt,
        (unsigned short*)mA, (unsigned short*)mB, L, n);
    block_sum_kernel<<<nb, 256, 0, stream>>>(cnt, bsum, binh, n);
    scan_final_kernel<<<nb, 256, 0, stream>>>(cnt, bsum, row_ptr, binh, binb, n, nb);
    fill_mm_perm_kernel<<<mmblocks + 1024 + nb, 256, 0, stream>>>(
        row, col, row_ptr, erank, ecol, e, n, x, wbt, mA,
        cnt, binb, perm, mmblocks);

    const int fblocks = (n + FNPB - 1) / FNPB;
    const __hip_bfloat16* mi = mA;
    __hip_bfloat16* mo = mB;
    __hip_bfloat16* hin = nullptr;   // layer 0 uses x (f32)
    __hip_bfloat16* hout = hb1;
    for (int l = 0; l < L; l++) {
        bool last = (l == L - 1);
        fused_layer_kernel<<<fblocks, 128, 0, stream>>>(
            (l == 0) ? x : nullptr, hin, mi,
            wbt + (size_t)(L + l) * 4096,
            last ? nullptr : (wbt + (size_t)(l + 1) * 4096),
            row_ptr, ecol, perm,
            conv_nw + (size_t)l * HIDDEN, hid_nw + (size_t)l * HIDDEN,
            last ? out : nullptr,
            last ? nullptr : hout,
            last ? nullptr : mo, n);
        __hip_bfloat16* tmp = (__hip_bfloat16*)mi; mi = mo; mo = tmp;
        hin = hout;
        hout = (hout == hb1) ? hb2 : hb1;
    }
}

// Round 8
// 280.107 us; speedup vs baseline: 2.8499x; 1.0417x over previous
//
#include <hip/hip_runtime.h>
#include <hip/hip_bf16.h>

#define HIDDEN 64
#define EPS 1e-5f
#define NPB 64            // nodes per block (mm_relu part)
#define FNPB 32           // nodes per fused block (2 waves x 16)
#define WST 72            // bf16 LDS row stride (shorts): 16B-aligned, breaks 128B aliasing
#define NBIN 33           // degree bins for counting sort (deg clamped to 32)

typedef __attribute__((ext_vector_type(8))) short bf16x8;   // MFMA A/B frag (4 VGPRs)
typedef __attribute__((ext_vector_type(4))) float f32x4;    // MFMA C/D frag

__device__ __forceinline__ unsigned short f2b(float x) {
    __hip_bfloat16 b = __float2bfloat16(x);
    return *(unsigned short*)&b;
}
__device__ __forceinline__ float b2f(unsigned short u) {
    unsigned int ui = (unsigned int)u << 16;
    return *(float*)&ui;
}
__device__ __forceinline__ float b2f_lo(unsigned int u) { unsigned int ui = u << 16; return *(float*)&ui; }
__device__ __forceinline__ float b2f_hi(unsigned int u) { unsigned int ui = u & 0xffff0000u; return *(float*)&ui; }
__device__ __forceinline__ unsigned int pk2(float a, float b) {
    return (unsigned int)f2b(a) | ((unsigned int)f2b(b) << 16);
}

// ---------------- CSR build (separate dispatches — grid.sync measured at
// ~100us/sync on gfx950 in round 4; launch overhead is far cheaper) ----------------

// merged: histogram+rank (blocks 0..1023) and weight-convert (blocks >=1024)
__global__ __launch_bounds__(256) void hist_wconv_kernel(
        const int* __restrict__ row, int* __restrict__ cnt, int* __restrict__ erank, int e,
        const float* __restrict__ cw, const float* __restrict__ hw,
        unsigned short* __restrict__ wbt,
        unsigned short* __restrict__ mA, unsigned short* __restrict__ mB,
        int L, int n) {
    int b = blockIdx.x;
    if (b < 1024) {
        int stride = 1024 * 256;
        for (int i = b * 256 + threadIdx.x; i < e; i += stride) {
            int r = row[i];
            erank[i] = atomicAdd(&cnt[r], 1);
        }
    } else {
        int idx = (b - 1024) * 256 + threadIdx.x;
        int total = 2 * L * 4096;
        if (idx < total) {
            int mat = idx >> 12;
            int rem = idx & 4095;
            const float* src = (mat < L) ? (cw + (size_t)mat * 4096) : (hw + (size_t)(mat - L) * 4096);
            wbt[idx] = f2b(src[rem]);
        } else if (idx < total + HIDDEN) {
            int k = idx - total;
            mA[(size_t)n * HIDDEN + k] = 0;   // zero dummy row (OOB gather target)
            mB[(size_t)n * HIDDEN + k] = 0;
        }
    }
}

// per-256-chunk sums for row_ptr scan + degree-bin histogram (for perm sort)
__global__ __launch_bounds__(256) void block_sum_kernel(const int* __restrict__ cnt,
                                                        int* __restrict__ bsum,
                                                        int* __restrict__ binh, int n) {
    __shared__ int wsum[4];
    __shared__ int lb[NBIN];
    int tid = threadIdx.x;
    if (tid < NBIN) lb[tid] = 0;
    __syncthreads();
    int i = blockIdx.x * 256 + tid;
    int v = (i < n) ? cnt[i] : 0;
    if (i < n) {
        int d = v > 32 ? 32 : v;
        atomicAdd(&lb[d], 1);
    }
#pragma unroll
    for (int off = 32; off > 0; off >>= 1) v += __shfl_xor(v, off, 64);
    if ((tid & 63) == 0) wsum[tid >> 6] = v;
    __syncthreads();
    if (tid == 0) bsum[blockIdx.x] = wsum[0] + wsum[1] + wsum[2] + wsum[3];
    if (tid < NBIN && lb[tid] > 0) atomicAdd(&binh[tid], lb[tid]);
}

// scan -> row_ptr; block 0 additionally turns binh into exclusive bases binb
__global__ __launch_bounds__(256) void scan_final_kernel(const int* __restrict__ cnt,
                                                         const int* __restrict__ bsum,
                                                         int* __restrict__ row_ptr,
                                                         const int* __restrict__ binh,
                                                         int* __restrict__ binb,
                                                         int n, int nb) {
    __shared__ int wred[4];
    __shared__ int wsum[4];
    __shared__ int wexcl[4];
    __shared__ int s_prev;
    __shared__ int s_tot;
    int b = blockIdx.x;
    int tid = threadIdx.x;
    int lane = tid & 63;
    int w = tid >> 6;
    if (b == 0 && tid == 0) {
        int run = 0;
#pragma unroll 1
        for (int j = 0; j < NBIN; j++) { binb[j] = run; run += binh[j]; }
    }
    int acc = 0;
    for (int j = tid; j < b; j += 256) acc += bsum[j];
#pragma unroll
    for (int off = 32; off > 0; off >>= 1) acc += __shfl_xor(acc, off, 64);
    if (lane == 0) wred[w] = acc;
    int i = b * 256 + tid;
    int v = (i < n) ? cnt[i] : 0;
    int sc = v;
#pragma unroll
    for (int off = 1; off < 64; off <<= 1) {
        int t = __shfl_up(sc, off, 64);
        if (lane >= off) sc += t;
    }
    if (lane == 63) wsum[w] = sc;
    __syncthreads();
    if (tid == 0) {
        s_prev = wred[0] + wred[1] + wred[2] + wred[3];
        int a = 0;
#pragma unroll
        for (int j = 0; j < 4; j++) { wexcl[j] = a; a += wsum[j]; }
        s_tot = a;
    }
    __syncthreads();
    if (i < n) row_ptr[i] = s_prev + wexcl[w] + (sc - v);
    if (b == nb - 1 && tid == 0) row_ptr[n] = s_prev + s_tot;
}

// ---------------- MFMA helpers ----------------

__device__ __forceinline__ void mfma_tile(const unsigned short* s_a,
                                          const unsigned short* s_b,
                                          int l16, int quad, int wbase, f32x4 acc[4]) {
    const unsigned short* ap = &s_a[(size_t)(wbase + l16) * WST + quad * 8];
    const unsigned short* bp = &s_b[(size_t)l16 * WST + quad * 8];
#pragma unroll
    for (int kt = 0; kt < 2; kt++) {
        bf16x8 a = *(const bf16x8*)(ap + kt * 32);
#pragma unroll
        for (int nt = 0; nt < 4; nt++) {
            bf16x8 b = *(const bf16x8*)(bp + (size_t)nt * 16 * WST + kt * 32);
            acc[nt] = __builtin_amdgcn_mfma_f32_16x16x32_bf16(a, b, acc[nt], 0, 0, 0);
        }
    }
}

// load a 64x64 bf16 weight matrix's B-fragments global -> registers (L2-hot 8KB)
__device__ __forceinline__ void load_wfrag(const unsigned short* __restrict__ w,
                                           int l16, int quad, bf16x8 wf[8]) {
    const unsigned short* wp = w + (size_t)l16 * 64 + quad * 8;
#pragma unroll
    for (int nt = 0; nt < 4; nt++) {
#pragma unroll
        for (int kt = 0; kt < 2; kt++)
            wf[nt * 2 + kt] = *(const bf16x8*)(wp + (size_t)nt * 16 * 64 + kt * 32);
    }
}

__device__ __forceinline__ void stage_wb(const unsigned short* __restrict__ wsrc,
                                         unsigned short* s_wb, int tid) {
    for (int i = tid; i < 512; i += 256) {
        int r = i >> 3, seg = i & 7;
        *(uint4*)(&s_wb[r * WST + seg * 8]) = ((const uint4*)(wsrc + r * 64))[seg];
    }
}

// accumulate 8 bf16 values (one uint4) into p[0..7] — unconditional
__device__ __forceinline__ void acc8(float* p, uint4 u) {
    p[0] += b2f_lo(u.x);
    p[1] += b2f_hi(u.x);
    p[2] += b2f_lo(u.y);
    p[3] += b2f_hi(u.y);
    p[4] += b2f_lo(u.z);
    p[5] += b2f_hi(u.z);
    p[6] += b2f_lo(u.w);
    p[7] += b2f_hi(u.w);
}

// ---------------- merged fill + initial conv matmul + perm scatter ----------------
// blocks [0, mmblocks):               m = bf16(relu(x @ cw0^T))
// blocks [mmblocks, mmblocks+1024):   CSR fill (8 row-classes x 128 sub)
// blocks [mmblocks+1024, +nb):        degree counting-sort scatter -> perm

__global__ __launch_bounds__(256) void fill_mm_perm_kernel(
        const int* __restrict__ row, const int* __restrict__ col,
        const int* __restrict__ row_ptr, const int* __restrict__ erank,
        int* __restrict__ ecol, int e, int n,
        const float* __restrict__ h, const unsigned short* __restrict__ wb,
        __hip_bfloat16* __restrict__ m,
        const int* __restrict__ cnt, int* __restrict__ binb, int* __restrict__ perm,
        int mmblocks) {
    __shared__ unsigned short s_hb[NPB * WST];
    __shared__ unsigned short s_wb[64 * WST];
    __shared__ int lbin[NBIN];
    __shared__ int lbase[NBIN];
    int tid = threadIdx.x;
    int bid = blockIdx.x;
    if (bid >= mmblocks + 1024) {
        // ---- perm scatter: counting sort by degree, 256 nodes per block ----
        int c = bid - (mmblocks + 1024);
        if (tid < NBIN) lbin[tid] = 0;
        __syncthreads();
        int i = c * 256 + tid;
        int d = -1, rank = 0;
        if (i < n) {
            int dv = cnt[i];
            d = dv > 32 ? 32 : dv;
            rank = atomicAdd(&lbin[d], 1);
        }
        __syncthreads();
        if (tid < NBIN && lbin[tid] > 0) lbase[tid] = atomicAdd(&binb[tid], lbin[tid]);
        __syncthreads();
        if (d >= 0) perm[lbase[d] + rank] = i;
        return;
    }
    if (bid >= mmblocks) {
        // ---- CSR fill (1024 blocks, 8 row-classes) ----
        int fb = bid - mmblocks;
        int cls = fb & 7;
        int sub = fb >> 3;
        int nsub = 128;
        int lo = (int)(((long long)n * cls) >> 3);
        int hi = (int)(((long long)n * (cls + 1)) >> 3);
        for (int i = sub * 256 + tid; i < e; i += nsub * 256) {
            int r = row[i];
            if (r >= lo && r < hi) {
                int pos = row_ptr[r] + erank[i];
                ecol[pos] = col[i];
            }
        }
        return;
    }
    // ---- mm_relu ----
    int base = bid * NPB;
    stage_wb(wb, s_wb, tid);
    for (int i = tid; i < 512; i += 256) {
        int r = i >> 3, seg = i & 7;
        if (base + r < n) {
            const float4* hp = (const float4*)(h + (size_t)(base + r) * HIDDEN + seg * 8);
            float4 ha = hp[0], hb = hp[1];
            uint4 p;
            p.x = pk2(ha.x, ha.y);
            p.y = pk2(ha.z, ha.w);
            p.z = pk2(hb.x, hb.y);
            p.w = pk2(hb.z, hb.w);
            *(uint4*)(&s_hb[r * WST + seg * 8]) = p;
        } else {
            *(uint4*)(&s_hb[r * WST + seg * 8]) = make_uint4(0u, 0u, 0u, 0u);
        }
    }
    __syncthreads();
    int lane = tid & 63, wave = tid >> 6;
    int quad = lane >> 4, l16 = lane & 15;
    int wbase = wave * 16;
    f32x4 acc[4];
    acc[0] = (f32x4){0.f,0.f,0.f,0.f}; acc[1] = (f32x4){0.f,0.f,0.f,0.f};
    acc[2] = (f32x4){0.f,0.f,0.f,0.f}; acc[3] = (f32x4){0.f,0.f,0.f,0.f};
    mfma_tile(s_hb, s_wb, l16, quad, wbase, acc);
    unsigned short* mo = (unsigned short*)m;
#pragma unroll
    for (int r = 0; r < 4; r++) {
        int node = base + wbase + quad * 4 + r;
        if (node < n) {
#pragma unroll
            for (int nt = 0; nt < 4; nt++)
                mo[(size_t)node * HIDDEN + nt * 16 + l16] = f2b(fmaxf(acc[nt][r], 0.f));
        }
    }
}

// ---------------- fused layer kernel ----------------
// Round-7 structure: 128 thr = 2 waves, 32 nodes; degree-sorted perm (wave's 16
// nodes have ~equal degree); barrier-free; both weight matrices global->register.
// NEW (r8): NO SHUFFLES in the gather loop. All 4 lanes of a group load the
// group's 4 neighbor indices DIRECTLY from ecol (same address -> one L1 line,
// broadcast). This removes 4 serialized ds_bpermute ops (~30cyc each) per
// iteration AND the cross-lane dependency that blocked software pipelining.
// Loop order: issue 8 gathers -> load NEXT iteration's indices (independent,
// overlaps gather latency) -> accumulate (waits on gathers) -> swap. The serial
// chain per iteration becomes max(gather latency, accumulate) instead of
// idxload + shuffle + gather + accumulate.
// OOB indices -> pre-zeroed dummy row n (adds +0.0f).
// Phase B: hidden MFMA + residual + rmsnorm.  Phase C: next conv MFMA -> relu.

__global__ __launch_bounds__(128, 6) void fused_layer_kernel(
        const float* hf, const __hip_bfloat16* hb_in,
        const __hip_bfloat16* __restrict__ m_in,
        const unsigned short* __restrict__ hwb,
        const unsigned short* cwb_next,
        const int* __restrict__ row_ptr, const int* __restrict__ ecol,
        const int* __restrict__ perm,
        const float* __restrict__ cnw, const float* __restrict__ hnw,
        float* out_f32, __hip_bfloat16* hb_new, __hip_bfloat16* m_out, int n) {
    __shared__ unsigned short s_hb[FNPB * WST];
    int tid = threadIdx.x;
    int base = blockIdx.x * FNPB;
    int lane = tid & 63, wave = tid >> 6;

    // ---- Phase A: 16 nodes per wave, 4 lanes (16 cols) per node ----
    int g = lane >> 2;          // node slot within wave tile (0..15)
    int sl = lane & 3;          // 16-column slice
    int nl = wave * 16 + g;     // LDS A-tile row
    int pidx = base + nl;       // position in degree-sorted order
    int node = (pidx < n) ? perm[pidx] : -1;

    const unsigned short* mi = (const unsigned short*)m_in;

    uint4 q0 = make_uint4(0u, 0u, 0u, 0u);
    uint4 q1 = make_uint4(0u, 0u, 0u, 0u);
    if (node >= 0) {
        float p[16];
        if (hf) {
            const float4* hp = (const float4*)(hf + (size_t)node * HIDDEN + 16 * sl);
            float4 v0 = hp[0], v1 = hp[1], v2 = hp[2], v3 = hp[3];
            p[0]=v0.x;  p[1]=v0.y;  p[2]=v0.z;  p[3]=v0.w;
            p[4]=v1.x;  p[5]=v1.y;  p[6]=v1.z;  p[7]=v1.w;
            p[8]=v2.x;  p[9]=v2.y;  p[10]=v2.z; p[11]=v2.w;
            p[12]=v3.x; p[13]=v3.y; p[14]=v3.z; p[15]=v3.w;
        } else {
            const uint4* hp = (const uint4*)((const unsigned short*)hb_in + (size_t)node * HIDDEN + 16 * sl);
            uint4 u0 = hp[0], u1 = hp[1];
            p[0]=b2f_lo(u0.x);  p[1]=b2f_hi(u0.x);
            p[2]=b2f_lo(u0.y);  p[3]=b2f_hi(u0.y);
            p[4]=b2f_lo(u0.z);  p[5]=b2f_hi(u0.z);
            p[6]=b2f_lo(u0.w);  p[7]=b2f_hi(u0.w);
            p[8]=b2f_lo(u1.x);  p[9]=b2f_hi(u1.x);
            p[10]=b2f_lo(u1.y); p[11]=b2f_hi(u1.y);
            p[12]=b2f_lo(u1.z); p[13]=b2f_hi(u1.z);
            p[14]=b2f_lo(u1.w); p[15]=b2f_hi(u1.w);
        }
        int beg = row_ptr[node];
        int end = row_ptr[node + 1];
        // prime: indices for the first 4-neighbor block (direct loads, no shuffle)
        int cj[4];
#pragma unroll
        for (int j = 0; j < 4; j++) {
            int idx = beg + j;
            cj[j] = (idx < end) ? ecol[idx] : n;   // OOB -> pre-zeroed dummy row
        }
        for (int b0 = beg; b0 < end; b0 += 4) {
            // issue this block's 8 gathers
            uint4 ua[4], ub[4];
#pragma unroll
            for (int j = 0; j < 4; j++) {
                const uint4* mp = (const uint4*)(mi + (size_t)cj[j] * HIDDEN + 16 * sl);
                ua[j] = mp[0];
                ub[j] = mp[1];
            }
            // load next block's indices while gathers are in flight
            int nj[4];
#pragma unroll
            for (int j = 0; j < 4; j++) {
                int idx = b0 + 4 + j;
                nj[j] = (idx < end) ? ecol[idx] : n;
            }
            // accumulate (waits on gathers; nj loads overlap)
#pragma unroll
            for (int j = 0; j < 4; j++) {
                acc8(p, ua[j]);
                acc8(p + 8, ub[j]);
            }
#pragma unroll
            for (int j = 0; j < 4; j++) cj[j] = nj[j];
        }
        float ss = 0.f;
#pragma unroll
        for (int k = 0; k < 16; k++) ss += p[k] * p[k];
        ss += __shfl_xor(ss, 1, 64);
        ss += __shfl_xor(ss, 2, 64);
        float inv = rsqrtf(ss * (1.0f / 64.0f) + EPS);
        const float4* cp = (const float4*)(cnw + 16 * sl);
        float4 c0 = cp[0], c1 = cp[1], c2 = cp[2], c3 = cp[3];
        q0.x = pk2(p[0]*inv*c0.x,  p[1]*inv*c0.y);
        q0.y = pk2(p[2]*inv*c0.z,  p[3]*inv*c0.w);
        q0.z = pk2(p[4]*inv*c1.x,  p[5]*inv*c1.y);
        q0.w = pk2(p[6]*inv*c1.z,  p[7]*inv*c1.w);
        q1.x = pk2(p[8]*inv*c2.x,  p[9]*inv*c2.y);
        q1.y = pk2(p[10]*inv*c2.z, p[11]*inv*c2.w);
        q1.z = pk2(p[12]*inv*c3.x, p[13]*inv*c3.y);
        q1.w = pk2(p[14]*inv*c3.z, p[15]*inv*c3.w);
    }
    *(uint4*)(&s_hb[(size_t)nl * WST + 16 * sl]) = q0;
    *(uint4*)(&s_hb[(size_t)nl * WST + 16 * sl + 8]) = q1;
    // NO barrier: A-tile rows are wave-private, weights come from global.

    // ---- Phase B: hidden matmul with register B-fragments ----
    int quad = lane >> 4, l16 = lane & 15;
    int wbase = wave * 16;
    bf16x8 wfh[8];
    load_wfrag(hwb, l16, quad, wfh);
    f32x4 acc[4];
    acc[0] = (f32x4){0.f,0.f,0.f,0.f}; acc[1] = (f32x4){0.f,0.f,0.f,0.f};
    acc[2] = (f32x4){0.f,0.f,0.f,0.f}; acc[3] = (f32x4){0.f,0.f,0.f,0.f};
    {
        const unsigned short* ap = &s_hb[(size_t)(wbase + l16) * WST + quad * 8];
#pragma unroll
        for (int kt = 0; kt < 2; kt++) {
            bf16x8 a = *(const bf16x8*)(ap + kt * 32);
#pragma unroll
            for (int nt = 0; nt < 4; nt++)
                acc[nt] = __builtin_amdgcn_mfma_f32_16x16x32_bf16(a, wfh[nt * 2 + kt], acc[nt], 0, 0, 0);
        }
    }

    // permuted node ids for this thread's 4 output rows (L1/L2-hot)
    int pr[4];
#pragma unroll
    for (int r = 0; r < 4; r++) {
        int pidx_r = base + wbase + quad * 4 + r;
        pr[r] = (pidx_r < n) ? perm[pidx_r] : -1;
    }

    float hv[4][4];
    float ssq[4] = {0.f, 0.f, 0.f, 0.f};
#pragma unroll
    for (int r = 0; r < 4; r++) {
        int nr = wbase + quad * 4 + r;
#pragma unroll
        for (int nt = 0; nt < 4; nt++) {
            float hres = b2f(s_hb[(size_t)nr * WST + nt * 16 + l16]);
            float v = hres + fmaxf(acc[nt][r], 0.f);
            hv[r][nt] = v;
            ssq[r] += v * v;
        }
    }
#pragma unroll
    for (int mk = 1; mk <= 8; mk <<= 1) {
#pragma unroll
        for (int r = 0; r < 4; r++) ssq[r] += __shfl_xor(ssq[r], mk, 64);
    }
    bf16x8 wfc[8];
    if (m_out) load_wfrag(cwb_next, l16, quad, wfc);   // L2-hot, hides under norm+stores
    float nwv[4];
#pragma unroll
    for (int nt = 0; nt < 4; nt++) nwv[nt] = hnw[nt * 16 + l16];
#pragma unroll
    for (int r = 0; r < 4; r++) {
        float inv = rsqrtf(ssq[r] * (1.0f / 64.0f) + EPS);
#pragma unroll
        for (int nt = 0; nt < 4; nt++) hv[r][nt] *= inv * nwv[nt];
    }
    if (out_f32) {
#pragma unroll
        for (int r = 0; r < 4; r++) {
            if (pr[r] >= 0) {
#pragma unroll
                for (int nt = 0; nt < 4; nt++)
                    out_f32[(size_t)pr[r] * HIDDEN + nt * 16 + l16] = hv[r][nt];
            }
        }
    }
    if (hb_new) {
        unsigned short* ho = (unsigned short*)hb_new;
#pragma unroll
        for (int r = 0; r < 4; r++) {
            if (pr[r] >= 0) {
#pragma unroll
                for (int nt = 0; nt < 4; nt++)
                    ho[(size_t)pr[r] * HIDDEN + nt * 16 + l16] = f2b(hv[r][nt]);
            }
        }
    }

    if (!m_out) return;

    // ---- D -> A layout (own rows only; intra-wave, no barrier) ----
#pragma unroll
    for (int r = 0; r < 4; r++) {
        int nr = wbase + quad * 4 + r;
#pragma unroll
        for (int nt = 0; nt < 4; nt++)
            s_hb[(size_t)nr * WST + nt * 16 + l16] = f2b(hv[r][nt]);
    }

    // ---- Phase C ----
    f32x4 acc2[4];
    acc2[0] = (f32x4){0.f,0.f,0.f,0.f}; acc2[1] = (f32x4){0.f,0.f,0.f,0.f};
    acc2[2] = (f32x4){0.f,0.f,0.f,0.f}; acc2[3] = (f32x4){0.f,0.f,0.f,0.f};
    {
        const unsigned short* ap = &s_hb[(size_t)(wbase + l16) * WST + quad * 8];
#pragma unroll
        for (int kt = 0; kt < 2; kt++) {
            bf16x8 a = *(const bf16x8*)(ap + kt * 32);
#pragma unroll
            for (int nt = 0; nt < 4; nt++)
                acc2[nt] = __builtin_amdgcn_mfma_f32_16x16x32_bf16(a, wfc[nt * 2 + kt], acc2[nt], 0, 0, 0);
        }
    }
    unsigned short* mo = (unsigned short*)m_out;
#pragma unroll
    for (int r = 0; r < 4; r++) {
        if (pr[r] >= 0) {
#pragma unroll
            for (int nt = 0; nt < 4; nt++)
                mo[(size_t)pr[r] * HIDDEN + nt * 16 + l16] = f2b(fmaxf(acc2[nt][r], 0.f));
        }
    }
}

// ---------------- launch ----------------

static inline size_t align_up(size_t x, size_t a) { return (x + a - 1) & ~(a - 1); }

extern "C" void kernel_launch(void* const* d_in, const int* in_sizes, int n_in,
                              void* d_out, int out_size, void* d_ws, size_t ws_size,
                              hipStream_t stream) {
    const float* x       = (const float*)d_in[0];
    const float* conv_w  = (const float*)d_in[1];
    const float* conv_nw = (const float*)d_in[2];
    const float* hid_w   = (const float*)d_in[3];
    const float* hid_nw  = (const float*)d_in[4];
    const int*   row     = (const int*)d_in[5];
    const int*   col     = (const int*)d_in[6];
    float* out = (float*)d_out;

    const int n = in_sizes[0] / HIDDEN;   // 100000
    const int e = in_sizes[5];            // 800000
    const int L = in_sizes[1] / 4096;     // 4

    // workspace layout (m buffers have n+1 rows: row n is the zero dummy row)
    size_t off = 0;
    char* ws = (char*)d_ws;
    __hip_bfloat16* mA = (__hip_bfloat16*)(ws + off);  off = align_up(off + (size_t)(n + 1) * HIDDEN * 2, 16);
    __hip_bfloat16* mB = (__hip_bfloat16*)(ws + off);  off = align_up(off + (size_t)(n + 1) * HIDDEN * 2, 16);
    __hip_bfloat16* hb1 = (__hip_bfloat16*)(ws + off); off = align_up(off + (size_t)n * HIDDEN * 2, 16);
    __hip_bfloat16* hb2 = (__hip_bfloat16*)(ws + off); off = align_up(off + (size_t)n * HIDDEN * 2, 16);
    unsigned short* wbt = (unsigned short*)(ws + off); off = align_up(off + (size_t)2 * L * 4096 * 2, 16);
    int* row_ptr = (int*)(ws + off);           off = align_up(off + (size_t)(n + 1) * 4, 16);
    int* cnt = (int*)(ws + off);               // cnt, binh, binb contiguous (one memset)
    int* binh = cnt + n;
    int* binb = binh + 64;
    off = align_up(off + (size_t)(n + 128) * 4, 16);
    int* perm = (int*)(ws + off);              off = align_up(off + (size_t)n * 4, 16);
    int* bsum = (int*)(ws + off);              off = align_up(off + (size_t)1024 * 4, 16);
    int* erank = (int*)(ws + off);             off = align_up(off + (size_t)e * 4, 16);
    int* ecol = (int*)(ws + off);              off = align_up(off + (size_t)e * 4, 16);

    const int nb = (n + 255) / 256;
    const int wconv_blocks = (2 * L * 4096 + HIDDEN + 255) / 256;
    const int mmblocks = (n + NPB - 1) / NPB;

    // CSR build + weight convert + degree sort (merged where independent)
    hipMemsetAsync(cnt, 0, (size_t)(n + 64) * 4, stream);   // cnt + binh
    hist_wconv_kernel<<<1024 + wconv_blocks, 256, 0, stream>>>(
        row, cnt, erank, e, conv_w, hid_w, wbt,
        (unsigned short*)mA, (unsigned short*)mB, L, n);
    block_sum_kernel<<<nb, 256, 0, stream>>>(cnt, bsum, binh, n);
    scan_final_kernel<<<nb, 256, 0, stream>>>(cnt, bsum, row_ptr, binh, binb, n, nb);
    fill_mm_perm_kernel<<<mmblocks + 1024 + nb, 256, 0, stream>>>(
        row, col, row_ptr, erank, ecol, e, n, x, wbt, mA,
        cnt, binb, perm, mmblocks);

    const int fblocks = (n + FNPB - 1) / FNPB;
    const __hip_bfloat16* mi = mA;
    __hip_bfloat16* mo = mB;
    __hip_bfloat16* hin = nullptr;   // layer 0 uses x (f32)
    __hip_bfloat16* hout = hb1;
    for (int l = 0; l < L; l++) {
        bool last = (l == L - 1);
        fused_layer_kernel<<<fblocks, 128, 0, stream>>>(
            (l == 0) ? x : nullptr, hin, mi,
            wbt + (size_t)(L + l) * 4096,
            last ? nullptr : (wbt + (size_t)(l + 1) * 4096),
            row_ptr, ecol, perm,
            conv_nw + (size_t)l * HIDDEN, hid_nw + (size_t)l * HIDDEN,
            last ? out : nullptr,
            last ? nullptr : hout,
            last ? nullptr : mo, n);
        __hip_bfloat16* tmp = (__hip_bfloat16*)mi; mi = mo; mo = tmp;
        hin = hout;
        hout = (hout == hb1) ? hb2 : hb1;
    }
}